// Round 1
// 879.151 us; speedup vs baseline: 1.9052x; 1.9052x over previous
//
#include <hip/hip_runtime.h>

typedef unsigned short u16;
typedef unsigned int   u32;

#define BB   64
#define TT   256
#define DIN  5881
#define DM   64
#define DI   128
#define NST  16
#define DTR  4
#define TCH  32      // timestep chunk
#define NCH  8       // chunks per batch

#define NROW (BB*TT)              // 16384 rows of the encoder GEMM
#define NKT  ((DIN+63)/64)        // 92 K-tiles of 64
#define ZBYTES  ((size_t)NROW*DM*2)       // z workspace: 2 MB bf16
#define WPBYTES ((size_t)NKT*8*64*16)     // packed W_enc panels: 736 KB

__device__ __forceinline__ float bf2f(u16 u) {
    union { u32 i; float f; } v; v.i = ((u32)u) << 16; return v.f;
}
__device__ __forceinline__ u16 f2bf(float f) {
    union { float f; u32 i; } v; v.f = f;
    u32 x = v.i;
    return (u16)((x + 0x7FFFu + ((x >> 16) & 1u)) >> 16);
}

typedef __attribute__((ext_vector_type(8))) short short8;
typedef __attribute__((ext_vector_type(4))) float floatx4;

// dtype-aware element loads
template<bool BF16>
__device__ __forceinline__ float ld1(const void* p, size_t i) {
    if (BF16) return bf2f(((const u16*)p)[i]);
    else      return ((const float*)p)[i];
}
template<bool BF16>
__device__ __forceinline__ u16 ldb(const void* p, size_t i) {   // load as bf16 bits
    if (BF16) return ((const u16*)p)[i];
    else      return f2bf(((const float*)p)[i]);
}
template<bool BF16>
__device__ __forceinline__ void st1(void* p, size_t i, float v) {
    if (BF16) ((u16*)p)[i] = f2bf(v);
    else      ((float*)p)[i] = v;
}

__device__ __forceinline__ short8 as_s8(uint4 v) {
    union { uint4 u; short8 s; } c; c.u = v; return c.s;
}

// ============================================================================
// Kernel 0: pack W_enc into MFMA B-fragment panels.
// Panel p = it*8 + nt*2 + kt holds, at uint4 index `lane`, the 8 bf16 elems
// W_enc[nt*16 + (lane&15)][it*64 + kt*32 + (lane>>4)*8 .. +7], K-tail zeroed.
// Makes encoder B-loads aligned + perfectly coalesced (raw W_enc rows have
// stride 5881*2 B = only 2B-aligned).
// ============================================================================
template<bool BF16>
__device__ __forceinline__ void pack_body(const void* Wenc, u16* wp) {
    int g = blockIdx.x * 256 + threadIdx.x;       // one 16B chunk per thread
    if (g >= NKT * 8 * 64) return;
    int lane = g & 63;  int p = g >> 6;           // panel id
    int kt = p & 1, nt = (p >> 1) & 3, it = p >> 3;
    int r16 = lane & 15, quad = lane >> 4;
    int n  = nt * 16 + r16;
    int k0 = it * 64 + kt * 32 + quad * 8;
    u32 w[4];
    #pragma unroll
    for (int j = 0; j < 4; ++j) {
        int ka = k0 + 2 * j;
        u32 lo = (ka     < DIN) ? (u32)ldb<BF16>(Wenc, (size_t)n * DIN + ka)     : 0u;
        u32 hi = (ka + 1 < DIN) ? (u32)ldb<BF16>(Wenc, (size_t)n * DIN + ka + 1) : 0u;
        w[j] = lo | (hi << 16);
    }
    *(uint4*)(wp + ((size_t)p * 64 + lane) * 8) = make_uint4(w[0], w[1], w[2], w[3]);
}

__global__ __launch_bounds__(256) void pack_wenc(const void* Wenc, const void* A_log, u16* wp) {
    if (((const u32*)A_log)[0] != 0u) pack_body<true >(Wenc, wp);
    else                              pack_body<false>(Wenc, wp);
}

// ============================================================================
// Kernel 1: encoder GEMM  z[16384,64] = input[16384,5881] @ W_enc^T + b_enc
// 256 blocks x 4 waves; each wave owns one 16-row M-tile. No LDS, no barriers:
// A-frags direct global->reg (u16 loads; odd row stride forbids wide loads),
// B-frags from packed panels (dwordx4). Depth-2 software pipeline.
// ============================================================================
template<bool BF16>
__device__ __forceinline__ void enc_load(const void* inp, const uint4* wp4,
        size_t arow, int it, int kq, int lane, bool tail,
        uint4 a[2], uint4 b[4][2]) {
    #pragma unroll
    for (int kt = 0; kt < 2; ++kt) {
        int k0 = it * 64 + kt * 32 + kq;
        u32 w[4];
        #pragma unroll
        for (int j = 0; j < 4; ++j) {
            u32 lo, hi;
            if (!tail) {
                lo = ldb<BF16>(inp, arow + k0 + 2 * j);
                hi = ldb<BF16>(inp, arow + k0 + 2 * j + 1);
            } else {
                int ka = k0 + 2 * j;
                lo = (ka     < DIN) ? (u32)ldb<BF16>(inp, arow + ka)     : 0u;
                hi = (ka + 1 < DIN) ? (u32)ldb<BF16>(inp, arow + ka + 1) : 0u;
            }
            w[j] = lo | (hi << 16);
        }
        a[kt] = make_uint4(w[0], w[1], w[2], w[3]);
    }
    const uint4* p = wp4 + (size_t)it * 512 + lane;
    #pragma unroll
    for (int nt = 0; nt < 4; ++nt)
        #pragma unroll
        for (int kt = 0; kt < 2; ++kt)
            b[nt][kt] = p[(nt * 2 + kt) * 64];
}

__device__ __forceinline__ void enc_mma(const uint4 a[2], const uint4 b[4][2], floatx4 acc[4]) {
    #pragma unroll
    for (int nt = 0; nt < 4; ++nt)
        #pragma unroll
        for (int kt = 0; kt < 2; ++kt)
            acc[nt] = __builtin_amdgcn_mfma_f32_16x16x32_bf16(
                          as_s8(a[kt]), as_s8(b[nt][kt]), acc[nt], 0, 0, 0);
}

template<bool BF16>
__device__ __forceinline__ void enc_body(const void* inp, const void* benc,
                                         const u16* wp, u16* z) {
    const int tid  = threadIdx.x;
    const int wave = tid >> 6, lane = tid & 63;
    const int r16  = lane & 15, quad = lane >> 4;
    const int m0   = blockIdx.x * 64 + wave * 16;
    const size_t arow = (size_t)(m0 + r16) * DIN;
    const int kq = quad * 8;
    const uint4* wp4 = (const uint4*)wp;

    floatx4 acc[4];
    #pragma unroll
    for (int nt = 0; nt < 4; ++nt) acc[nt] = (floatx4){0, 0, 0, 0};

    uint4 aA[2], bA[4][2], aB[2], bB[4][2];
    enc_load<BF16>(inp, wp4, arow, 0, kq, lane, false, aA, bA);
    for (int it = 0; it < NKT; it += 2) {
        enc_load<BF16>(inp, wp4, arow, it + 1, kq, lane, (it + 1) == NKT - 1, aB, bB);
        enc_mma(aA, bA, acc);
        if (it + 2 < NKT)
            enc_load<BF16>(inp, wp4, arow, it + 2, kq, lane, false, aA, bA);
        enc_mma(aB, bB, acc);
    }

    // epilogue: + b_enc, store bf16 z. C/D map: col=r16 (n), row=quad*4+reg (m)
    #pragma unroll
    for (int nt = 0; nt < 4; ++nt) {
        float bi = ld1<BF16>(benc, nt * 16 + r16);
        #pragma unroll
        for (int reg = 0; reg < 4; ++reg) {
            int row = m0 + quad * 4 + reg;
            z[(size_t)row * DM + nt * 16 + r16] = f2bf(acc[nt][reg] + bi);
        }
    }
}

__global__ __launch_bounds__(256) void enc_gemm(const void* inp, const void* benc,
                                                const void* A_log, const u16* wp, u16* z) {
    if (((const u32*)A_log)[0] != 0u) enc_body<true >(inp, benc, wp, z);
    else                              enc_body<false>(inp, benc, wp, z);
}

// ============================================================================
// Kernel 2: mamba + heads. Structure identical to previous kernel, with the
// 92-iteration encoder GEMM replaced by a 4 KB coalesced load of z per chunk.
// ============================================================================
template<bool BF16>
__device__ __forceinline__ void body(
        const void* W_in,
        const void* conv_w, const void* conv_b, const void* W_x, const void* W_dt,
        const void* b_dt,   const void* A_log,  const void* D_skip, const void* W_out,
        const void* W_fc,   const void* b_fc,   const void* W_mu, const void* b_mu,
        const void* W_sig,  const void* b_sig,  const u16* zws, void* out,
        u16* zc, u16* xl, u16* gl, u16* xcb,
        float* xd2, u16* dtl, float* yb, float* es, float* xs) {

    const int b    = blockIdx.x;
    const int tid  = threadIdx.x;
    const int wave = tid >> 6, lane = tid & 63;
    const int quad = lane >> 4, r16 = lane & 15;
    const int dd   = tid & 127;

    // ---- per-thread parameter preloads ----
    float cw[4], cb, wdt[4], bdt;
    #pragma unroll
    for (int k = 0; k < 4; ++k) cw[k] = ld1<BF16>(conv_w, dd * 4 + k);
    cb = ld1<BF16>(conv_b, dd);
    #pragma unroll
    for (int r = 0; r < 4; ++r) wdt[r] = ld1<BF16>(W_dt, dd * 4 + r);
    bdt = ld1<BF16>(b_dt, dd);

    float Areg[NST], hreg[NST], Dv = 0.f, accy = 0.f;
    #pragma unroll
    for (int n = 0; n < NST; ++n) hreg[n] = 0.f;
    if (tid < DI) {
        #pragma unroll
        for (int n = 0; n < NST; ++n) Areg[n] = -expf(ld1<BF16>(A_log, tid * NST + n));
        Dv = ld1<BF16>(D_skip, tid);
    } else {
        #pragma unroll
        for (int n = 0; n < NST; ++n) Areg[n] = 0.f;
    }

    // xz B-frags: W_in rows (wave*64 + nt*16 + r16), K=64 (2 k-tiles)
    short8 win[4][2];
    #pragma unroll
    for (int nt = 0; nt < 4; ++nt)
        #pragma unroll
        for (int kt = 0; kt < 2; ++kt) {
            size_t base = (size_t)(wave * 64 + nt * 16 + r16) * DM + kt * 32 + quad * 8;
            short8 v;
            #pragma unroll
            for (int e = 0; e < 8; ++e) v[e] = (short)ldb<BF16>(W_in, base + e);
            win[nt][kt] = v;
        }

    // xdbl B-frags: W_x rows j = wave*16 + r16 (waves 0..2), K=128 (4 k-tiles)
    short8 wx[4];
    {
        int j = wave * 16 + r16;
        #pragma unroll
        for (int kt = 0; kt < 4; ++kt) {
            short8 v = (short8){0,0,0,0,0,0,0,0};
            if (wave < 3 && j < DTR + 2 * NST) {
                size_t base = (size_t)j * DI + kt * 32 + quad * 8;
                #pragma unroll
                for (int e = 0; e < 8; ++e) v[e] = (short)ldb<BF16>(W_x, base + e);
            }
            wx[kt] = v;
        }
    }

    // zero conv halo rows 0..2
    for (int i = tid; i < 3 * 128; i += 256) xl[i] = 0;
    __syncthreads();

    const int rowbase = b * TT;

    for (int c = 0; c < NCH; ++c) {
        // ===== 1) load precomputed z chunk [32 x 64] bf16 -> zc =====
        {
            int t = tid >> 3, n0 = (tid & 7) * 8;
            const u16* zsrc = zws + (size_t)(rowbase + c * TCH + t) * DM + n0;
            *(uint4*)(&zc[t * 72 + n0]) = *(const uint4*)zsrc;
        }
        __syncthreads();

        // ===== 2) xz = z @ W_in^T (MFMA), split x / gate =====
        floatx4 xza[2][4];
        #pragma unroll
        for (int mt = 0; mt < 2; ++mt)
            #pragma unroll
            for (int nt = 0; nt < 4; ++nt) xza[mt][nt] = (floatx4){0,0,0,0};
        #pragma unroll
        for (int kt = 0; kt < 2; ++kt) {
            short8 a0 = *(const short8*)(&zc[(0 * 16 + r16) * 72 + kt * 32 + quad * 8]);
            short8 a1 = *(const short8*)(&zc[(1 * 16 + r16) * 72 + kt * 32 + quad * 8]);
            #pragma unroll
            for (int nt = 0; nt < 4; ++nt) {
                xza[0][nt] = __builtin_amdgcn_mfma_f32_16x16x32_bf16(a0, win[nt][kt], xza[0][nt], 0, 0, 0);
                xza[1][nt] = __builtin_amdgcn_mfma_f32_16x16x32_bf16(a1, win[nt][kt], xza[1][nt], 0, 0, 0);
            }
        }
        #pragma unroll
        for (int mt = 0; mt < 2; ++mt)
            #pragma unroll
            for (int nt = 0; nt < 4; ++nt) {
                int n = wave * 64 + nt * 16 + r16;
                #pragma unroll
                for (int reg = 0; reg < 4; ++reg) {
                    int t = mt * 16 + quad * 4 + reg;
                    u16 v = f2bf(xza[mt][nt][reg]);
                    if (n < DI) xl[(t + 3) * 128 + n] = v;
                    else        gl[t * 128 + (n - DI)] = v;
                }
            }
        __syncthreads();

        // ===== 3) causal conv + SiLU -> xcb =====
        for (int it2 = tid; it2 < TCH * DI; it2 += 256) {
            int t = it2 >> 7, d = it2 & 127;
            float a = cb;
            #pragma unroll
            for (int k = 0; k < 4; ++k) a += bf2f(xl[(t + k) * 128 + d]) * cw[k];
            float s = a / (1.f + expf(-a));
            xcb[t * 136 + d] = f2bf(s);
        }
        __syncthreads();

        // ===== 4) x_dbl = xconv @ W_x^T (MFMA, waves 0..2) =====
        {
            floatx4 xda0 = (floatx4){0,0,0,0}, xda1 = (floatx4){0,0,0,0};
            if (wave < 3) {
                #pragma unroll
                for (int kt = 0; kt < 4; ++kt) {
                    short8 a0 = *(const short8*)(&xcb[(0 * 16 + r16) * 136 + kt * 32 + quad * 8]);
                    short8 a1 = *(const short8*)(&xcb[(1 * 16 + r16) * 136 + kt * 32 + quad * 8]);
                    xda0 = __builtin_amdgcn_mfma_f32_16x16x32_bf16(a0, wx[kt], xda0, 0, 0, 0);
                    xda1 = __builtin_amdgcn_mfma_f32_16x16x32_bf16(a1, wx[kt], xda1, 0, 0, 0);
                }
                int j = wave * 16 + r16;
                if (j < DTR + 2 * NST) {
                    #pragma unroll
                    for (int reg = 0; reg < 4; ++reg) {
                        xd2[(0 * 16 + quad * 4 + reg) * 40 + j] = xda0[reg];
                        xd2[(1 * 16 + quad * 4 + reg) * 40 + j] = xda1[reg];
                    }
                }
            }
        }
        __syncthreads();

        // ===== 5) dt = softplus(x_dbl[:, :4] @ W_dt^T + b_dt) =====
        for (int it2 = tid; it2 < TCH * DI; it2 += 256) {
            int t = it2 >> 7, d = it2 & 127;
            float v = bdt;
            #pragma unroll
            for (int r = 0; r < 4; ++r) v += xd2[t * 40 + r] * wdt[r];
            float sp = (v > 20.f) ? v : log1pf(expf(v));
            dtl[d * 33 + t] = f2bf(sp);
        }
        __syncthreads();

        // ===== 6) selective scan (threads 0..127); halo copy (128..255) =====
        if (tid < DI) {
            int d = tid;
            for (int t = 0; t < TCH; ++t) {
                float dtv = bf2f(dtl[d * 33 + t]);
                float xcv = bf2f(xcb[t * 136 + d]);
                float g   = bf2f(gl[t * 128 + d]);
                float dx  = dtv * xcv;
                const floatx4* Bp = (const floatx4*)(&xd2[t * 40 + DTR]);
                const floatx4* Cp = (const floatx4*)(&xd2[t * 40 + DTR + NST]);
                float y = 0.f;
                #pragma unroll
                for (int q = 0; q < 4; ++q) {
                    floatx4 Bv = Bp[q], Cv = Cp[q];
                    #pragma unroll
                    for (int e = 0; e < 4; ++e) {
                        int n = q * 4 + e;
                        float dA = expf(dtv * Areg[n]);
                        hreg[n] = dA * hreg[n] + dx * Bv[e];
                        y += hreg[n] * Cv[e];
                    }
                }
                y += Dv * xcv;
                y *= g / (1.f + expf(-g));
                accy += y;
            }
        } else {
            for (int it2 = tid - 128; it2 < 3 * 128; it2 += 128)
                xl[it2] = xl[32 * 128 + it2];
        }
        __syncthreads();
    }

    // ===== heads =====
    if (tid < DI) yb[tid] = accy * (1.f / (float)TT);
    __syncthreads();
    if (tid < DM) {
        float s = 0.f;
        #pragma unroll 8
        for (int k = 0; k < DI; ++k) s += yb[k] * ld1<BF16>(W_out, (size_t)tid * DI + k);
        es[tid] = s;
    }
    __syncthreads();
    if (tid < 128) {
        float s = ld1<BF16>(b_fc, tid);
        #pragma unroll 8
        for (int k = 0; k < DM; ++k) s += es[k] * ld1<BF16>(W_fc, (size_t)tid * DM + k);
        float th = tanhf(s);
        float xv = th > 0.f ? th : expm1f(th);
        xs[tid] = xv;
        st1<BF16>(out, (size_t)b * 128 + tid, xv);
    }
    __syncthreads();
    for (int j = tid; j < 512; j += 256) {
        int o = j & 255;
        bool is_mu = (j < 256);
        const void* w = is_mu ? W_mu : W_sig;
        float s = ld1<BF16>(is_mu ? b_mu : b_sig, o);
        #pragma unroll 8
        for (int k = 0; k < 128; ++k) s += xs[k] * ld1<BF16>(w, (size_t)o * 128 + k);
        if (is_mu) {
            st1<BF16>(out, 8192 + (size_t)b * 256 + o, s);
        } else {
            float e = s > 0.f ? s : expm1f(s);
            st1<BF16>(out, 8192 + 16384 + (size_t)b * 256 + o, e + 1.f + 1e-14f);
        }
    }
}

__global__ __launch_bounds__(256) void fused_mamba(
        const void* W_in,
        const void* conv_w, const void* conv_b, const void* W_x, const void* W_dt,
        const void* b_dt,   const void* A_log,  const void* D_skip, const void* W_out,
        const void* W_fc,   const void* b_fc,   const void* W_mu, const void* b_mu,
        const void* W_sig,  const void* b_sig,  const u16* zws, void* out) {
    __shared__ __align__(16) u16  zc[32 * 72];
    __shared__ __align__(16) u16  xl[35 * 128];
    __shared__ __align__(16) u16  gl[32 * 128];
    __shared__ __align__(16) u16  xcb[32 * 136];
    __shared__ __align__(16) float xd2[32 * 40];
    __shared__ __align__(16) u16  dtl[128 * 33];
    __shared__ float yb[128];
    __shared__ float es[64];
    __shared__ float xs[128];

    bool isbf = (((const u32*)A_log)[0] != 0u);
    if (isbf)
        body<true >(W_in,conv_w,conv_b,W_x,W_dt,b_dt,A_log,D_skip,
                    W_out,W_fc,b_fc,W_mu,b_mu,W_sig,b_sig,zws,out,
                    zc,xl,gl,xcb,xd2,dtl,yb,es,xs);
    else
        body<false>(W_in,conv_w,conv_b,W_x,W_dt,b_dt,A_log,D_skip,
                    W_out,W_fc,b_fc,W_mu,b_mu,W_sig,b_sig,zws,out,
                    zc,xl,gl,xcb,xd2,dtl,yb,es,xs);
}

extern "C" void kernel_launch(void* const* d_in, const int* in_sizes, int n_in,
                              void* d_out, int out_size, void* d_ws, size_t ws_size,
                              hipStream_t stream) {
    (void)in_sizes; (void)n_in; (void)ws_size; (void)out_size;
    u16* zws = (u16*)d_ws;
    u16* wp  = (u16*)((char*)d_ws + ZBYTES);

    // 0) pack W_enc into aligned MFMA panels (184*256 threads = exactly NKT*8*64 chunks)
    pack_wenc<<<184, 256, 0, stream>>>(d_in[1], d_in[9], wp);
    // 1) encoder GEMM across the whole chip (256 blocks)
    enc_gemm<<<256, 256, 0, stream>>>(d_in[0], d_in[2], d_in[9], wp, zws);
    // 2) sequential mamba + heads (64 blocks, one per batch)
    fused_mamba<<<BB, 256, 0, stream>>>(d_in[3],
                                        d_in[4], d_in[5], d_in[6], d_in[7],
                                        d_in[8], d_in[9], d_in[10], d_in[11],
                                        d_in[12], d_in[13], d_in[14], d_in[15],
                                        d_in[16], d_in[17], zws, d_out);
}

// Round 2
// 717.165 us; speedup vs baseline: 2.3355x; 1.2259x over previous
//
#include <hip/hip_runtime.h>

typedef unsigned short u16;
typedef unsigned int   u32;

#define BB   64
#define TT   256
#define DIN  5881
#define DM   64
#define DI   128
#define NST  16
#define DTR  4
#define TCH  32      // timestep chunk
#define NCH  8       // chunks per batch

#define NROW (BB*TT)              // 16384 rows of the encoder GEMM
#define NKT  92                   // K-tiles of 64 (92*64 = 5888 >= 5881)
#define KHALF 46                  // K-split half (in tiles)

// ---- workspace layout (bytes) ----
// [0, 2MB)      zws  bf16 [16384][64]   encoder output (biased)
// [2MB, 3MB)    wp   packed W_enc panels (736 KB)
// [3MB, 35MB)   psg  f32x4 [16384][128] {dt, dt*xc, silu(g), D*xc*silu(g)}
// [35MB, 37MB)  BCg  f32 [16384][32]    {B[16], C[16]}
// [37MB, ...)   ysg  f32 [64][128]      scan output (sum over t,n)
#define ZWS_OFF  ((size_t)0)
#define WP_OFF   ((size_t)2*1024*1024)
#define PSG_OFF  ((size_t)3*1024*1024)
#define BC_OFF   ((size_t)35*1024*1024)
#define YS_OFF   ((size_t)37*1024*1024)

__device__ __forceinline__ float bf2f(u16 u) {
    union { u32 i; float f; } v; v.i = ((u32)u) << 16; return v.f;
}
__device__ __forceinline__ u16 f2bf(float f) {
    union { float f; u32 i; } v; v.f = f;
    u32 x = v.i;
    return (u16)((x + 0x7FFFu + ((x >> 16) & 1u)) >> 16);
}

typedef __attribute__((ext_vector_type(8))) short short8;
typedef __attribute__((ext_vector_type(4))) float floatx4;

template<bool BF16>
__device__ __forceinline__ float ld1(const void* p, size_t i) {
    if (BF16) return bf2f(((const u16*)p)[i]);
    else      return ((const float*)p)[i];
}
template<bool BF16>
__device__ __forceinline__ u16 ldb(const void* p, size_t i) {
    if (BF16) return ((const u16*)p)[i];
    else      return f2bf(((const float*)p)[i]);
}
template<bool BF16>
__device__ __forceinline__ void st1(void* p, size_t i, float v) {
    if (BF16) ((u16*)p)[i] = f2bf(v);
    else      ((float*)p)[i] = v;
}

__device__ __forceinline__ short8 as_s8(uint4 v) {
    union { uint4 u; short8 s; } c; c.u = v; return c.s;
}

// ============================================================================
// Kernel 0: pack W_enc into MFMA B-fragment panels (aligned, K-tail zeroed).
// ============================================================================
template<bool BF16>
__device__ __forceinline__ void pack_body(const void* Wenc, u16* wp) {
    int g = blockIdx.x * 256 + threadIdx.x;
    if (g >= NKT * 8 * 64) return;
    int lane = g & 63;  int p = g >> 6;
    int kt = p & 1, nt = (p >> 1) & 3, it = p >> 3;
    int r16 = lane & 15, quad = lane >> 4;
    int n  = nt * 16 + r16;
    int k0 = it * 64 + kt * 32 + quad * 8;
    u32 w[4];
    #pragma unroll
    for (int j = 0; j < 4; ++j) {
        int ka = k0 + 2 * j;
        u32 lo = (ka     < DIN) ? (u32)ldb<BF16>(Wenc, (size_t)n * DIN + ka)     : 0u;
        u32 hi = (ka + 1 < DIN) ? (u32)ldb<BF16>(Wenc, (size_t)n * DIN + ka + 1) : 0u;
        w[j] = lo | (hi << 16);
    }
    *(uint4*)(wp + ((size_t)p * 64 + lane) * 8) = make_uint4(w[0], w[1], w[2], w[3]);
}

__global__ __launch_bounds__(256) void pack_wenc(const void* Wenc, const void* A_log, u16* wp) {
    if (((const u32*)A_log)[0] != 0u) pack_body<true >(Wenc, wp);
    else                              pack_body<false>(Wenc, wp);
}

// ============================================================================
// Kernel 1: encoder GEMM with in-block K-split.
// 256 blocks x 8 waves; waves 0-3 = K[0,2944), waves 4-7 = K[2944,5888).
// Each wave: one 16-row M-tile, 46 K-tiles, depth-2 pipeline, no staging LDS.
// f32 partial reduce through LDS, +bias, bf16 store.
// ============================================================================
template<bool BF16>
__device__ __forceinline__ void enc_load(const void* inp, const uint4* wp4,
        size_t arow, int it, int kq, int lane, bool tail,
        uint4 a[2], uint4 b[4][2]) {
    #pragma unroll
    for (int kt = 0; kt < 2; ++kt) {
        int k0 = it * 64 + kt * 32 + kq;
        u32 w[4];
        #pragma unroll
        for (int j = 0; j < 4; ++j) {
            u32 lo, hi;
            if (!tail) {
                lo = ldb<BF16>(inp, arow + k0 + 2 * j);
                hi = ldb<BF16>(inp, arow + k0 + 2 * j + 1);
            } else {
                int ka = k0 + 2 * j;
                lo = (ka     < DIN) ? (u32)ldb<BF16>(inp, arow + ka)     : 0u;
                hi = (ka + 1 < DIN) ? (u32)ldb<BF16>(inp, arow + ka + 1) : 0u;
            }
            w[j] = lo | (hi << 16);
        }
        a[kt] = make_uint4(w[0], w[1], w[2], w[3]);
    }
    const uint4* p = wp4 + (size_t)it * 512 + lane;
    #pragma unroll
    for (int nt = 0; nt < 4; ++nt)
        #pragma unroll
        for (int kt = 0; kt < 2; ++kt)
            b[nt][kt] = p[(nt * 2 + kt) * 64];
}

__device__ __forceinline__ void enc_mma(const uint4 a[2], const uint4 b[4][2], floatx4 acc[4]) {
    #pragma unroll
    for (int nt = 0; nt < 4; ++nt)
        #pragma unroll
        for (int kt = 0; kt < 2; ++kt)
            acc[nt] = __builtin_amdgcn_mfma_f32_16x16x32_bf16(
                          as_s8(a[kt]), as_s8(b[nt][kt]), acc[nt], 0, 0, 0);
}

template<bool BF16>
__device__ __forceinline__ void enc_body(const void* inp, const void* benc,
                                         const u16* wp, u16* z, float* zred) {
    const int tid  = threadIdx.x;
    const int wave = tid >> 6, lane = tid & 63;
    const int r16  = lane & 15, quad = lane >> 4;
    const int half = wave >> 2, mt = wave & 3;
    const int m0   = blockIdx.x * 64 + mt * 16;
    const size_t arow = (size_t)(m0 + r16) * DIN;
    const int kq = quad * 8;
    const uint4* wp4 = (const uint4*)wp;
    const int it0 = half * KHALF, itN = it0 + KHALF;

    floatx4 acc[4];
    #pragma unroll
    for (int nt = 0; nt < 4; ++nt) acc[nt] = (floatx4){0, 0, 0, 0};

    uint4 aA[2], bA[4][2], aB[2], bB[4][2];
    enc_load<BF16>(inp, wp4, arow, it0, kq, lane, false, aA, bA);
    for (int it = it0; it < itN; it += 2) {
        enc_load<BF16>(inp, wp4, arow, it + 1, kq, lane, (it + 1) == NKT - 1, aB, bB);
        enc_mma(aA, bA, acc);
        if (it + 2 < itN)
            enc_load<BF16>(inp, wp4, arow, it + 2, kq, lane, false, aA, bA);
        enc_mma(aB, bB, acc);
    }

    if (half == 0) {
        #pragma unroll
        for (int nt = 0; nt < 4; ++nt)
            #pragma unroll
            for (int reg = 0; reg < 4; ++reg)
                zred[(mt * 16 + quad * 4 + reg) * 64 + nt * 16 + r16] = acc[nt][reg];
    }
    __syncthreads();
    if (half == 1) {
        #pragma unroll
        for (int nt = 0; nt < 4; ++nt) {
            float bi = ld1<BF16>(benc, nt * 16 + r16);
            #pragma unroll
            for (int reg = 0; reg < 4; ++reg) {
                int lr = mt * 16 + quad * 4 + reg;
                float v = zred[lr * 64 + nt * 16 + r16] + acc[nt][reg] + bi;
                z[(size_t)(blockIdx.x * 64 + lr) * DM + nt * 16 + r16] = f2bf(v);
            }
        }
    }
}

__global__ __launch_bounds__(512) void enc_gemm(const void* inp, const void* benc,
                                                const void* A_log, const u16* wp, u16* z) {
    __shared__ __align__(16) float zred[64 * 64];
    if (((const u32*)A_log)[0] != 0u) enc_body<true >(inp, benc, wp, z, zred);
    else                              enc_body<false>(inp, benc, wp, z, zred);
}

// ============================================================================
// Kernel 2: prep — parallel over (batch, chunk). 512 blocks x 256 threads.
// Recomputes the 3-row conv halo (16-row halo tile) from z so chunks are
// independent. Emits per-(t,d) float4 {dt, dt*xc, silu(g), D*xc*silu(g)}
// and per-(t) B/C (f32) to workspace.
// ============================================================================
template<bool BF16>
__device__ __forceinline__ void prep_body(
        const void* W_in, const void* conv_w, const void* conv_b,
        const void* W_x, const void* W_dt, const void* b_dt, const void* D_skip,
        const u16* zws, float4* psg, float* BCg,
        u16* zc, u16* xl, u16* gl, u16* xcb, float* xd2) {

    const int bid  = blockIdx.x;
    const int b    = bid >> 3, c = bid & 7;
    const int tid  = threadIdx.x;
    const int wave = tid >> 6, lane = tid & 63;
    const int quad = lane >> 4, r16 = lane & 15;
    const int dd   = tid & 127;

    float cw[4], cb, wdt[4], bdt, Dv;
    #pragma unroll
    for (int k = 0; k < 4; ++k) cw[k] = ld1<BF16>(conv_w, dd * 4 + k);
    cb = ld1<BF16>(conv_b, dd);
    #pragma unroll
    for (int r = 0; r < 4; ++r) wdt[r] = ld1<BF16>(W_dt, dd * 4 + r);
    bdt = ld1<BF16>(b_dt, dd);
    Dv  = ld1<BF16>(D_skip, dd);

    // xz B-frags: W_in rows (wave*64 + nt*16 + r16), K=64 (2 k-tiles)
    short8 win[4][2];
    #pragma unroll
    for (int nt = 0; nt < 4; ++nt)
        #pragma unroll
        for (int kt = 0; kt < 2; ++kt) {
            size_t base = (size_t)(wave * 64 + nt * 16 + r16) * DM + kt * 32 + quad * 8;
            short8 v;
            #pragma unroll
            for (int e = 0; e < 8; ++e) v[e] = (short)ldb<BF16>(W_in, base + e);
            win[nt][kt] = v;
        }

    // xdbl B-frags: W_x rows j = wave*16 + r16 (waves 0..2), K=128 (4 k-tiles)
    short8 wx[4];
    {
        int j = wave * 16 + r16;
        #pragma unroll
        for (int kt = 0; kt < 4; ++kt) {
            short8 v = (short8){0,0,0,0,0,0,0,0};
            if (wave < 3 && j < DTR + 2 * NST) {
                size_t base = (size_t)j * DI + kt * 32 + quad * 8;
                #pragma unroll
                for (int e = 0; e < 8; ++e) v[e] = (short)ldb<BF16>(W_x, base + e);
            }
            wx[kt] = v;
        }
    }

    // ---- stage z: 48 rows covering t in [c*32-16, c*32+32), t<0 -> 0 ----
    const int base_t = c * 32 - 16;
    for (int i = tid; i < 48 * 64; i += 256) {
        int rr = i >> 6, nn = i & 63, t = base_t + rr;
        u16 v = 0;
        if (t >= 0) v = zws[(size_t)(b * TT + t) * DM + nn];
        zc[rr * 72 + nn] = v;
    }
    __syncthreads();

    // ---- xz = z @ W_in^T (MFMA, 3 m-tiles); x rows rr>=13, gate rr>=16 ----
    floatx4 xza[3][4];
    #pragma unroll
    for (int mt = 0; mt < 3; ++mt)
        #pragma unroll
        for (int nt = 0; nt < 4; ++nt) xza[mt][nt] = (floatx4){0,0,0,0};
    #pragma unroll
    for (int kt = 0; kt < 2; ++kt) {
        short8 a[3];
        #pragma unroll
        for (int mt = 0; mt < 3; ++mt)
            a[mt] = *(const short8*)(&zc[(mt * 16 + r16) * 72 + kt * 32 + quad * 8]);
        #pragma unroll
        for (int nt = 0; nt < 4; ++nt)
            #pragma unroll
            for (int mt = 0; mt < 3; ++mt)
                xza[mt][nt] = __builtin_amdgcn_mfma_f32_16x16x32_bf16(a[mt], win[nt][kt], xza[mt][nt], 0, 0, 0);
    }
    #pragma unroll
    for (int mt = 0; mt < 3; ++mt)
        #pragma unroll
        for (int nt = 0; nt < 4; ++nt) {
            int n = wave * 64 + nt * 16 + r16;
            #pragma unroll
            for (int reg = 0; reg < 4; ++reg) {
                int rr = mt * 16 + quad * 4 + reg;
                u16 v = f2bf(xza[mt][nt][reg]);
                if (n < DI) { if (rr >= 13) xl[(rr - 13) * 128 + n] = v; }
                else if (rr >= 16) gl[(rr - 16) * 128 + (n - DI)] = v;
            }
        }
    __syncthreads();

    // ---- causal conv + SiLU -> xcb ----
    for (int it2 = tid; it2 < TCH * DI; it2 += 256) {
        int t = it2 >> 7, d = it2 & 127;
        float a = cb;
        #pragma unroll
        for (int k = 0; k < 4; ++k) a += bf2f(xl[(t + k) * 128 + d]) * cw[k];
        float s = a / (1.f + expf(-a));
        xcb[t * 136 + d] = f2bf(s);
    }
    __syncthreads();

    // ---- x_dbl = xconv @ W_x^T (MFMA, waves 0..2) ----
    {
        floatx4 xda0 = (floatx4){0,0,0,0}, xda1 = (floatx4){0,0,0,0};
        if (wave < 3) {
            #pragma unroll
            for (int kt = 0; kt < 4; ++kt) {
                short8 a0 = *(const short8*)(&xcb[(0 * 16 + r16) * 136 + kt * 32 + quad * 8]);
                short8 a1 = *(const short8*)(&xcb[(1 * 16 + r16) * 136 + kt * 32 + quad * 8]);
                xda0 = __builtin_amdgcn_mfma_f32_16x16x32_bf16(a0, wx[kt], xda0, 0, 0, 0);
                xda1 = __builtin_amdgcn_mfma_f32_16x16x32_bf16(a1, wx[kt], xda1, 0, 0, 0);
            }
            int j = wave * 16 + r16;
            if (j < DTR + 2 * NST) {
                #pragma unroll
                for (int reg = 0; reg < 4; ++reg) {
                    xd2[(0 * 16 + quad * 4 + reg) * 40 + j] = xda0[reg];
                    xd2[(1 * 16 + quad * 4 + reg) * 40 + j] = xda1[reg];
                }
            }
        }
    }
    __syncthreads();

    // ---- pointwise finalize: dt (f32), dx, sg, skip; write psg + BC ----
    const size_t rowb = (size_t)b * TT + c * 32;
    for (int it2 = tid; it2 < TCH * DI; it2 += 256) {
        int t = it2 >> 7, d = it2 & 127;
        float v = bdt;
        #pragma unroll
        for (int r = 0; r < 4; ++r) v += xd2[t * 40 + r] * wdt[r];
        float sp  = (v > 20.f) ? v : log1pf(expf(v));
        float xcv = bf2f(xcb[t * 136 + d]);
        float g   = bf2f(gl[t * 128 + d]);
        float sg  = g / (1.f + expf(-g));
        psg[(rowb + t) * DI + d] = make_float4(sp, sp * xcv, sg, Dv * xcv * sg);
    }
    for (int i = tid; i < TCH * 32; i += 256) {
        int t = i >> 5, j = i & 31;
        BCg[(rowb + t) * 32 + j] = xd2[t * 40 + DTR + j];
    }
}

__global__ __launch_bounds__(256) void prep(
        const void* W_in, const void* conv_w, const void* conv_b,
        const void* W_x, const void* W_dt, const void* b_dt, const void* D_skip,
        const void* A_log, const u16* zws, float4* psg, float* BCg) {
    __shared__ __align__(16) u16  zc[48 * 72];
    __shared__ __align__(16) u16  xl[35 * 128];
    __shared__ __align__(16) u16  gl[32 * 128];
    __shared__ __align__(16) u16  xcb[32 * 136];
    __shared__ __align__(16) float xd2[32 * 40];
    if (((const u32*)A_log)[0] != 0u)
        prep_body<true >(W_in, conv_w, conv_b, W_x, W_dt, b_dt, D_skip, zws, psg, BCg,
                         zc, xl, gl, xcb, xd2);
    else
        prep_body<false>(W_in, conv_w, conv_b, W_x, W_dt, b_dt, D_skip, zws, psg, BCg,
                         zc, xl, gl, xcb, xd2);
}

// ============================================================================
// Kernel 3: selective scan. 256 blocks = (b, d-quarter), 512 threads:
// one thread per (d, n) chain. No LDS; register ping-pong prefetch (static
// indices only). n-reduction deferred to end via sg-scaled partials.
// ============================================================================
__device__ __forceinline__ void scan_ld(const float4* psg, const float* BCg,
        size_t pbase, size_t bbase, int s, float4 (&P)[8], float (&Bv)[8], float (&Cv)[8]) {
    #pragma unroll
    for (int q = 0; q < 8; ++q) {
        int r = s * 8 + q;
        P[q]  = psg[pbase + (size_t)r * DI];
        Bv[q] = BCg[bbase + (size_t)r * 32];
        Cv[q] = BCg[bbase + (size_t)r * 32 + 16];
    }
}
__device__ __forceinline__ void scan_cmp(const float4 (&P)[8], const float (&Bv)[8],
        const float (&Cv)[8], float Av, int n, float& h, float& acc, float& sk) {
    #pragma unroll
    for (int q = 0; q < 8; ++q) {
        float e = expf(P[q].x * Av);
        h   = fmaf(e, h, P[q].y * Bv[q]);
        acc = fmaf(h * Cv[q], P[q].z, acc);
        sk += (n == 0) ? P[q].w : 0.f;
    }
}

__global__ __launch_bounds__(512) void scan_k(const void* A_log, const float4* psg,
        const float* BCg, float* ysg) {
    const int tid = threadIdx.x;
    const int b = blockIdx.x >> 2, dq = blockIdx.x & 3;
    const int dl = tid >> 4, n = tid & 15;
    const int d = dq * 32 + dl;
    const bool isbf = (((const u32*)A_log)[0] != 0u);
    float al = isbf ? bf2f(((const u16*)A_log)[d * NST + n])
                    : ((const float*)A_log)[d * NST + n];
    const float Av = -expf(al);
    const size_t rb = (size_t)b * TT;
    const size_t pbase = rb * DI + d;
    const size_t bbase = rb * 32 + n;

    float4 pA[8], pB[8];
    float  BA[8], CA[8], Bb[8], Cb[8];
    float h = 0.f, acc = 0.f, sk = 0.f;

    scan_ld(psg, BCg, pbase, bbase, 0, pA, BA, CA);
    for (int s = 0; s < 32; s += 2) {
        scan_ld(psg, BCg, pbase, bbase, s + 1, pB, Bb, Cb);
        scan_cmp(pA, BA, CA, Av, n, h, acc, sk);
        if (s + 2 < 32) scan_ld(psg, BCg, pbase, bbase, s + 2, pA, BA, CA);
        scan_cmp(pB, Bb, Cb, Av, n, h, acc, sk);
    }
    acc += __shfl_xor(acc, 1);
    acc += __shfl_xor(acc, 2);
    acc += __shfl_xor(acc, 4);
    acc += __shfl_xor(acc, 8);
    if (n == 0) ysg[(size_t)b * DI + d] = acc + sk;
}

// ============================================================================
// Kernel 4: heads. 64 blocks x 256 threads.
// ============================================================================
template<bool BF16>
__device__ __forceinline__ void heads_body(
        const void* W_out, const void* W_fc, const void* b_fc,
        const void* W_mu, const void* b_mu, const void* W_sig, const void* b_sig,
        const float* ysg, void* out, float* yb, float* es, float* xs) {
    const int b = blockIdx.x, tid = threadIdx.x;
    if (tid < DI) yb[tid] = ysg[(size_t)b * DI + tid] * (1.f / (float)TT);
    __syncthreads();
    if (tid < DM) {
        float s = 0.f;
        #pragma unroll 8
        for (int k = 0; k < DI; ++k) s += yb[k] * ld1<BF16>(W_out, (size_t)tid * DI + k);
        es[tid] = s;
    }
    __syncthreads();
    if (tid < 128) {
        float s = ld1<BF16>(b_fc, tid);
        #pragma unroll 8
        for (int k = 0; k < DM; ++k) s += es[k] * ld1<BF16>(W_fc, (size_t)tid * DM + k);
        float th = tanhf(s);
        float xv = th > 0.f ? th : expm1f(th);
        xs[tid] = xv;
        st1<BF16>(out, (size_t)b * 128 + tid, xv);
    }
    __syncthreads();
    for (int j = tid; j < 512; j += 256) {
        int o = j & 255;
        bool is_mu = (j < 256);
        const void* w = is_mu ? W_mu : W_sig;
        float s = ld1<BF16>(is_mu ? b_mu : b_sig, o);
        #pragma unroll 8
        for (int k = 0; k < 128; ++k) s += xs[k] * ld1<BF16>(w, (size_t)o * 128 + k);
        if (is_mu) {
            st1<BF16>(out, 8192 + (size_t)b * 256 + o, s);
        } else {
            float e = s > 0.f ? s : expm1f(s);
            st1<BF16>(out, 8192 + 16384 + (size_t)b * 256 + o, e + 1.f + 1e-14f);
        }
    }
}

__global__ __launch_bounds__(256) void heads_k(
        const void* W_out, const void* W_fc, const void* b_fc,
        const void* W_mu, const void* b_mu, const void* W_sig, const void* b_sig,
        const void* A_log, const float* ysg, void* out) {
    __shared__ float yb[128];
    __shared__ float es[64];
    __shared__ float xs[128];
    if (((const u32*)A_log)[0] != 0u)
        heads_body<true >(W_out, W_fc, b_fc, W_mu, b_mu, W_sig, b_sig, ysg, out, yb, es, xs);
    else
        heads_body<false>(W_out, W_fc, b_fc, W_mu, b_mu, W_sig, b_sig, ysg, out, yb, es, xs);
}

extern "C" void kernel_launch(void* const* d_in, const int* in_sizes, int n_in,
                              void* d_out, int out_size, void* d_ws, size_t ws_size,
                              hipStream_t stream) {
    (void)in_sizes; (void)n_in; (void)ws_size; (void)out_size;
    char* ws = (char*)d_ws;
    u16*    zws = (u16*)(ws + ZWS_OFF);
    u16*    wp  = (u16*)(ws + WP_OFF);
    float4* psg = (float4*)(ws + PSG_OFF);
    float*  BCg = (float*)(ws + BC_OFF);
    float*  ysg = (float*)(ws + YS_OFF);

    // 0) pack W_enc into aligned MFMA panels
    pack_wenc<<<184, 256, 0, stream>>>(d_in[1], d_in[9], wp);
    // 1) encoder GEMM, in-block K-split (8 waves/block, 2 waves/SIMD)
    enc_gemm<<<256, 512, 0, stream>>>(d_in[0], d_in[2], d_in[9], wp, zws);
    // 2) parallel prep over (batch, chunk)
    prep<<<512, 256, 0, stream>>>(d_in[3], d_in[4], d_in[5], d_in[6], d_in[7],
                                  d_in[8], d_in[10], d_in[9], zws, psg, BCg);
    // 3) selective scan, one thread per (d, n) chain
    scan_k<<<256, 512, 0, stream>>>(d_in[9], psg, BCg, ysg);
    // 4) heads
    heads_k<<<64, 256, 0, stream>>>(d_in[11], d_in[12], d_in[13], d_in[14],
                                    d_in[15], d_in[16], d_in[17], d_in[9], ysg, d_out);
}

// Round 3
// 642.281 us; speedup vs baseline: 2.6078x; 1.1166x over previous
//
#include <hip/hip_runtime.h>

typedef unsigned short u16;
typedef unsigned int   u32;

#define BB   64
#define TT   256
#define DIN  5881
#define DM   64
#define DI   128
#define NST  16
#define DTR  4
#define TCH  32      // timestep chunk
#define NCH  8       // chunks per batch

#define NROW (BB*TT)              // 16384 rows of the encoder GEMM
#define NKT  92                   // K-tiles of 64 (92*64 = 5888 >= 5881)
#define KQRT 23                   // K-split quarter (in tiles): 4*23 = 92

// ---- workspace layout (bytes) ----
// [0, 2MB)      zws  bf16 [16384][64]   encoder output (biased)
// [2MB, 3MB)    wp   packed W_enc panels (736 KB)
// [3MB, 35MB)   psg  f32x4 [16384][128] {dt, dt*xc, silu(g), D*xc*silu(g)}
// [35MB, 37MB)  BCg  f32 [16384][32]    {B[16], C[16]}
// [37MB, ...)   ysg  f32 [64][128]      scan output (sum over t,n)
#define ZWS_OFF  ((size_t)0)
#define WP_OFF   ((size_t)2*1024*1024)
#define PSG_OFF  ((size_t)3*1024*1024)
#define BC_OFF   ((size_t)35*1024*1024)
#define YS_OFF   ((size_t)37*1024*1024)

__device__ __forceinline__ float bf2f(u16 u) {
    union { u32 i; float f; } v; v.i = ((u32)u) << 16; return v.f;
}
__device__ __forceinline__ u16 f2bf(float f) {
    union { float f; u32 i; } v; v.f = f;
    u32 x = v.i;
    return (u16)((x + 0x7FFFu + ((x >> 16) & 1u)) >> 16);
}

typedef __attribute__((ext_vector_type(8))) short short8;
typedef __attribute__((ext_vector_type(4))) float floatx4;

template<bool BF16>
__device__ __forceinline__ float ld1(const void* p, size_t i) {
    if (BF16) return bf2f(((const u16*)p)[i]);
    else      return ((const float*)p)[i];
}
template<bool BF16>
__device__ __forceinline__ u16 ldb(const void* p, size_t i) {
    if (BF16) return ((const u16*)p)[i];
    else      return f2bf(((const float*)p)[i]);
}
template<bool BF16>
__device__ __forceinline__ void st1(void* p, size_t i, float v) {
    if (BF16) ((u16*)p)[i] = f2bf(v);
    else      ((float*)p)[i] = v;
}

__device__ __forceinline__ short8 as_s8(uint4 v) {
    union { uint4 u; short8 s; } c; c.u = v; return c.s;
}

// ============================================================================
// Kernel 0: pack W_enc into MFMA B-fragment panels (aligned, K-tail zeroed).
// ============================================================================
template<bool BF16>
__device__ __forceinline__ void pack_body(const void* Wenc, u16* wp) {
    int g = blockIdx.x * 256 + threadIdx.x;
    if (g >= NKT * 8 * 64) return;
    int lane = g & 63;  int p = g >> 6;
    int kt = p & 1, nt = (p >> 1) & 3, it = p >> 3;
    int r16 = lane & 15, quad = lane >> 4;
    int n  = nt * 16 + r16;
    int k0 = it * 64 + kt * 32 + quad * 8;
    u32 w[4];
    #pragma unroll
    for (int j = 0; j < 4; ++j) {
        int ka = k0 + 2 * j;
        u32 lo = (ka     < DIN) ? (u32)ldb<BF16>(Wenc, (size_t)n * DIN + ka)     : 0u;
        u32 hi = (ka + 1 < DIN) ? (u32)ldb<BF16>(Wenc, (size_t)n * DIN + ka + 1) : 0u;
        w[j] = lo | (hi << 16);
    }
    *(uint4*)(wp + ((size_t)p * 64 + lane) * 8) = make_uint4(w[0], w[1], w[2], w[3]);
}

__global__ __launch_bounds__(256) void pack_wenc(const void* Wenc, const void* A_log, u16* wp) {
    if (((const u32*)A_log)[0] != 0u) pack_body<true >(Wenc, wp);
    else                              pack_body<false>(Wenc, wp);
}

// ============================================================================
// Kernel 1: encoder GEMM  z[16384,64] = input[16384,5881] @ W_enc^T + b_enc
// 1024 blocks x 4 waves (16 waves/CU). Block = one 16-row M-tile; waves split
// K 4 ways (23 tiles each). A staged via COALESCED u16 loads (lane l reads
// element l of row j: one 128B line per instr) into a wave-private LDS tile
// (stride 72, 16B-aligned fragment reads). Reg->LDS single-buffer pipeline,
// no barriers in the K-loop. f32 4-way LDS reduce + bias at the end.
// ============================================================================
template<bool BF16>
__device__ __forceinline__ void enc_loadr(const void* inp, int m0, int it, int lane,
                                          u16 (&rg)[16]) {
    const size_t kb = (size_t)it * 64 + lane;
    if (it != NKT - 1) {
        #pragma unroll
        for (int j = 0; j < 16; ++j)
            rg[j] = ldb<BF16>(inp, (size_t)(m0 + j) * DIN + kb);
    } else {
        bool ok = kb < DIN;
        #pragma unroll
        for (int j = 0; j < 16; ++j)
            rg[j] = ok ? ldb<BF16>(inp, (size_t)(m0 + j) * DIN + kb) : (u16)0;
    }
}

__device__ __forceinline__ void enc_write(u16* ms, int lane, const u16 (&rg)[16]) {
    #pragma unroll
    for (int j = 0; j < 16; ++j) ms[j * 72 + lane] = rg[j];
}

__device__ __forceinline__ void enc_compute(int it, const uint4* wp4, int lane,
                                            int r16, int quad, const u16* ms,
                                            floatx4 (&acc)[4]) {
    uint4 b[4][2];
    const uint4* p = wp4 + (size_t)it * 512 + lane;
    #pragma unroll
    for (int nt = 0; nt < 4; ++nt)
        #pragma unroll
        for (int kt = 0; kt < 2; ++kt)
            b[nt][kt] = p[(nt * 2 + kt) * 64];
    short8 a0 = *(const short8*)(ms + r16 * 72 +  0 + quad * 8);
    short8 a1 = *(const short8*)(ms + r16 * 72 + 32 + quad * 8);
    #pragma unroll
    for (int nt = 0; nt < 4; ++nt) {
        acc[nt] = __builtin_amdgcn_mfma_f32_16x16x32_bf16(a0, as_s8(b[nt][0]), acc[nt], 0, 0, 0);
        acc[nt] = __builtin_amdgcn_mfma_f32_16x16x32_bf16(a1, as_s8(b[nt][1]), acc[nt], 0, 0, 0);
    }
}

template<bool BF16>
__device__ __forceinline__ void enc_body(const void* inp, const void* benc,
                                         const u16* wp, u16* z,
                                         u16* stg, float* zred) {
    const int tid  = threadIdx.x;
    const int wave = tid >> 6, lane = tid & 63;
    const int r16  = lane & 15, quad = lane >> 4;
    const int m0   = blockIdx.x * 16;
    const uint4* wp4 = (const uint4*)wp;
    u16* ms = stg + wave * (16 * 72);
    const int it0 = wave * KQRT;

    floatx4 acc[4];
    #pragma unroll
    for (int nt = 0; nt < 4; ++nt) acc[nt] = (floatx4){0, 0, 0, 0};

    u16 rgA[16], rgB[16];
    enc_loadr<BF16>(inp, m0, it0, lane, rgA);
    int it = it0;
    #pragma unroll 1
    for (int p = 0; p < (KQRT - 1) / 2; ++p, it += 2) {
        enc_write(ms, lane, rgA);
        enc_loadr<BF16>(inp, m0, it + 1, lane, rgB);
        enc_compute(it, wp4, lane, r16, quad, ms, acc);
        enc_write(ms, lane, rgB);
        enc_loadr<BF16>(inp, m0, it + 2, lane, rgA);
        enc_compute(it + 1, wp4, lane, r16, quad, ms, acc);
    }
    // epilogue tile: it == it0 + 22
    enc_write(ms, lane, rgA);
    enc_compute(it, wp4, lane, r16, quad, ms, acc);

    // ---- 4-way f32 reduce + bias ----
    #pragma unroll
    for (int nt = 0; nt < 4; ++nt) {
        int col = nt * 16 + r16;
        #pragma unroll
        for (int reg = 0; reg < 4; ++reg) {
            int row = quad * 4 + reg;
            zred[wave * 1024 + row * 64 + col] = acc[nt][reg];
        }
    }
    __syncthreads();
    #pragma unroll
    for (int rep = 0; rep < 4; ++rep) {
        int o = rep * 256 + tid;           // o = row*64 + col
        int col = o & 63;
        float s = zred[o] + zred[1024 + o] + zred[2048 + o] + zred[3072 + o]
                + ld1<BF16>(benc, col);
        z[(size_t)(m0 + (o >> 6)) * DM + col] = f2bf(s);
    }
}

__global__ __launch_bounds__(256) void enc_gemm(const void* inp, const void* benc,
                                                const void* A_log, const u16* wp, u16* z) {
    __shared__ __align__(16) u16   stg[4 * 16 * 72];   // 9216 B
    __shared__ __align__(16) float zred[4 * 1024];     // 16384 B
    if (((const u32*)A_log)[0] != 0u) enc_body<true >(inp, benc, wp, z, stg, zred);
    else                              enc_body<false>(inp, benc, wp, z, stg, zred);
}

// ============================================================================
// Kernel 2: prep — parallel over (batch, chunk). 512 blocks x 256 threads.
// Recomputes the 3-row conv halo (16-row halo tile) from z so chunks are
// independent. Emits per-(t,d) float4 {dt, dt*xc, silu(g), D*xc*silu(g)}
// and per-(t) B/C (f32) to workspace.
// ============================================================================
template<bool BF16>
__device__ __forceinline__ void prep_body(
        const void* W_in, const void* conv_w, const void* conv_b,
        const void* W_x, const void* W_dt, const void* b_dt, const void* D_skip,
        const u16* zws, float4* psg, float* BCg,
        u16* zc, u16* xl, u16* gl, u16* xcb, float* xd2) {

    const int bid  = blockIdx.x;
    const int b    = bid >> 3, c = bid & 7;
    const int tid  = threadIdx.x;
    const int wave = tid >> 6, lane = tid & 63;
    const int quad = lane >> 4, r16 = lane & 15;
    const int dd   = tid & 127;

    float cw[4], cb, wdt[4], bdt, Dv;
    #pragma unroll
    for (int k = 0; k < 4; ++k) cw[k] = ld1<BF16>(conv_w, dd * 4 + k);
    cb = ld1<BF16>(conv_b, dd);
    #pragma unroll
    for (int r = 0; r < 4; ++r) wdt[r] = ld1<BF16>(W_dt, dd * 4 + r);
    bdt = ld1<BF16>(b_dt, dd);
    Dv  = ld1<BF16>(D_skip, dd);

    // xz B-frags: W_in rows (wave*64 + nt*16 + r16), K=64 (2 k-tiles)
    short8 win[4][2];
    #pragma unroll
    for (int nt = 0; nt < 4; ++nt)
        #pragma unroll
        for (int kt = 0; kt < 2; ++kt) {
            size_t base = (size_t)(wave * 64 + nt * 16 + r16) * DM + kt * 32 + quad * 8;
            short8 v;
            #pragma unroll
            for (int e = 0; e < 8; ++e) v[e] = (short)ldb<BF16>(W_in, base + e);
            win[nt][kt] = v;
        }

    // xdbl B-frags: W_x rows j = wave*16 + r16 (waves 0..2), K=128 (4 k-tiles)
    short8 wx[4];
    {
        int j = wave * 16 + r16;
        #pragma unroll
        for (int kt = 0; kt < 4; ++kt) {
            short8 v = (short8){0,0,0,0,0,0,0,0};
            if (wave < 3 && j < DTR + 2 * NST) {
                size_t base = (size_t)j * DI + kt * 32 + quad * 8;
                #pragma unroll
                for (int e = 0; e < 8; ++e) v[e] = (short)ldb<BF16>(W_x, base + e);
            }
            wx[kt] = v;
        }
    }

    // ---- stage z: 48 rows covering t in [c*32-16, c*32+32), t<0 -> 0 ----
    const int base_t = c * 32 - 16;
    for (int i = tid; i < 48 * 64; i += 256) {
        int rr = i >> 6, nn = i & 63, t = base_t + rr;
        u16 v = 0;
        if (t >= 0) v = zws[(size_t)(b * TT + t) * DM + nn];
        zc[rr * 72 + nn] = v;
    }
    __syncthreads();

    // ---- xz = z @ W_in^T (MFMA, 3 m-tiles); x rows rr>=13, gate rr>=16 ----
    floatx4 xza[3][4];
    #pragma unroll
    for (int mt = 0; mt < 3; ++mt)
        #pragma unroll
        for (int nt = 0; nt < 4; ++nt) xza[mt][nt] = (floatx4){0,0,0,0};
    #pragma unroll
    for (int kt = 0; kt < 2; ++kt) {
        short8 a[3];
        #pragma unroll
        for (int mt = 0; mt < 3; ++mt)
            a[mt] = *(const short8*)(&zc[(mt * 16 + r16) * 72 + kt * 32 + quad * 8]);
        #pragma unroll
        for (int nt = 0; nt < 4; ++nt)
            #pragma unroll
            for (int mt = 0; mt < 3; ++mt)
                xza[mt][nt] = __builtin_amdgcn_mfma_f32_16x16x32_bf16(a[mt], win[nt][kt], xza[mt][nt], 0, 0, 0);
    }
    #pragma unroll
    for (int mt = 0; mt < 3; ++mt)
        #pragma unroll
        for (int nt = 0; nt < 4; ++nt) {
            int n = wave * 64 + nt * 16 + r16;
            #pragma unroll
            for (int reg = 0; reg < 4; ++reg) {
                int rr = mt * 16 + quad * 4 + reg;
                u16 v = f2bf(xza[mt][nt][reg]);
                if (n < DI) { if (rr >= 13) xl[(rr - 13) * 128 + n] = v; }
                else if (rr >= 16) gl[(rr - 16) * 128 + (n - DI)] = v;
            }
        }
    __syncthreads();

    // ---- causal conv + SiLU -> xcb ----
    for (int it2 = tid; it2 < TCH * DI; it2 += 256) {
        int t = it2 >> 7, d = it2 & 127;
        float a = cb;
        #pragma unroll
        for (int k = 0; k < 4; ++k) a += bf2f(xl[(t + k) * 128 + d]) * cw[k];
        float s = a / (1.f + expf(-a));
        xcb[t * 136 + d] = f2bf(s);
    }
    __syncthreads();

    // ---- x_dbl = xconv @ W_x^T (MFMA, waves 0..2) ----
    {
        floatx4 xda0 = (floatx4){0,0,0,0}, xda1 = (floatx4){0,0,0,0};
        if (wave < 3) {
            #pragma unroll
            for (int kt = 0; kt < 4; ++kt) {
                short8 a0 = *(const short8*)(&xcb[(0 * 16 + r16) * 136 + kt * 32 + quad * 8]);
                short8 a1 = *(const short8*)(&xcb[(1 * 16 + r16) * 136 + kt * 32 + quad * 8]);
                xda0 = __builtin_amdgcn_mfma_f32_16x16x32_bf16(a0, wx[kt], xda0, 0, 0, 0);
                xda1 = __builtin_amdgcn_mfma_f32_16x16x32_bf16(a1, wx[kt], xda1, 0, 0, 0);
            }
            int j = wave * 16 + r16;
            if (j < DTR + 2 * NST) {
                #pragma unroll
                for (int reg = 0; reg < 4; ++reg) {
                    xd2[(0 * 16 + quad * 4 + reg) * 40 + j] = xda0[reg];
                    xd2[(1 * 16 + quad * 4 + reg) * 40 + j] = xda1[reg];
                }
            }
        }
    }
    __syncthreads();

    // ---- pointwise finalize: dt (f32), dx, sg, skip; write psg + BC ----
    const size_t rowb = (size_t)b * TT + c * 32;
    for (int it2 = tid; it2 < TCH * DI; it2 += 256) {
        int t = it2 >> 7, d = it2 & 127;
        float v = bdt;
        #pragma unroll
        for (int r = 0; r < 4; ++r) v += xd2[t * 40 + r] * wdt[r];
        float sp  = (v > 20.f) ? v : log1pf(expf(v));
        float xcv = bf2f(xcb[t * 136 + d]);
        float g   = bf2f(gl[t * 128 + d]);
        float sg  = g / (1.f + expf(-g));
        psg[(rowb + t) * DI + d] = make_float4(sp, sp * xcv, sg, Dv * xcv * sg);
    }
    for (int i = tid; i < TCH * 32; i += 256) {
        int t = i >> 5, j = i & 31;
        BCg[(rowb + t) * 32 + j] = xd2[t * 40 + DTR + j];
    }
}

__global__ __launch_bounds__(256) void prep(
        const void* W_in, const void* conv_w, const void* conv_b,
        const void* W_x, const void* W_dt, const void* b_dt, const void* D_skip,
        const void* A_log, const u16* zws, float4* psg, float* BCg) {
    __shared__ __align__(16) u16  zc[48 * 72];
    __shared__ __align__(16) u16  xl[35 * 128];
    __shared__ __align__(16) u16  gl[32 * 128];
    __shared__ __align__(16) u16  xcb[32 * 136];
    __shared__ __align__(16) float xd2[32 * 40];
    if (((const u32*)A_log)[0] != 0u)
        prep_body<true >(W_in, conv_w, conv_b, W_x, W_dt, b_dt, D_skip, zws, psg, BCg,
                         zc, xl, gl, xcb, xd2);
    else
        prep_body<false>(W_in, conv_w, conv_b, W_x, W_dt, b_dt, D_skip, zws, psg, BCg,
                         zc, xl, gl, xcb, xd2);
}

// ============================================================================
// Kernel 3: selective scan. 256 blocks = (b, d-quarter), 512 threads:
// one thread per (d, n) chain. No LDS; register ping-pong prefetch (static
// indices only). n-reduction deferred to end via sg-scaled partials.
// ============================================================================
__device__ __forceinline__ void scan_ld(const float4* psg, const float* BCg,
        size_t pbase, size_t bbase, int s, float4 (&P)[8], float (&Bv)[8], float (&Cv)[8]) {
    #pragma unroll
    for (int q = 0; q < 8; ++q) {
        int r = s * 8 + q;
        P[q]  = psg[pbase + (size_t)r * DI];
        Bv[q] = BCg[bbase + (size_t)r * 32];
        Cv[q] = BCg[bbase + (size_t)r * 32 + 16];
    }
}
__device__ __forceinline__ void scan_cmp(const float4 (&P)[8], const float (&Bv)[8],
        const float (&Cv)[8], float Av, int n, float& h, float& acc, float& sk) {
    #pragma unroll
    for (int q = 0; q < 8; ++q) {
        float e = expf(P[q].x * Av);
        h   = fmaf(e, h, P[q].y * Bv[q]);
        acc = fmaf(h * Cv[q], P[q].z, acc);
        sk += (n == 0) ? P[q].w : 0.f;
    }
}

__global__ __launch_bounds__(512) void scan_k(const void* A_log, const float4* psg,
        const float* BCg, float* ysg) {
    const int tid = threadIdx.x;
    const int b = blockIdx.x >> 2, dq = blockIdx.x & 3;
    const int dl = tid >> 4, n = tid & 15;
    const int d = dq * 32 + dl;
    const bool isbf = (((const u32*)A_log)[0] != 0u);
    float al = isbf ? bf2f(((const u16*)A_log)[d * NST + n])
                    : ((const float*)A_log)[d * NST + n];
    const float Av = -expf(al);
    const size_t rb = (size_t)b * TT;
    const size_t pbase = rb * DI + d;
    const size_t bbase = rb * 32 + n;

    float4 pA[8], pB[8];
    float  BA[8], CA[8], Bb[8], Cb[8];
    float h = 0.f, acc = 0.f, sk = 0.f;

    scan_ld(psg, BCg, pbase, bbase, 0, pA, BA, CA);
    for (int s = 0; s < 32; s += 2) {
        scan_ld(psg, BCg, pbase, bbase, s + 1, pB, Bb, Cb);
        scan_cmp(pA, BA, CA, Av, n, h, acc, sk);
        if (s + 2 < 32) scan_ld(psg, BCg, pbase, bbase, s + 2, pA, BA, CA);
        scan_cmp(pB, Bb, Cb, Av, n, h, acc, sk);
    }
    acc += __shfl_xor(acc, 1);
    acc += __shfl_xor(acc, 2);
    acc += __shfl_xor(acc, 4);
    acc += __shfl_xor(acc, 8);
    if (n == 0) ysg[(size_t)b * DI + d] = acc + sk;
}

// ============================================================================
// Kernel 4: heads. 64 blocks x 256 threads.
// ============================================================================
template<bool BF16>
__device__ __forceinline__ void heads_body(
        const void* W_out, const void* W_fc, const void* b_fc,
        const void* W_mu, const void* b_mu, const void* W_sig, const void* b_sig,
        const float* ysg, void* out, float* yb, float* es, float* xs) {
    const int b = blockIdx.x, tid = threadIdx.x;
    if (tid < DI) yb[tid] = ysg[(size_t)b * DI + tid] * (1.f / (float)TT);
    __syncthreads();
    if (tid < DM) {
        float s = 0.f;
        #pragma unroll 8
        for (int k = 0; k < DI; ++k) s += yb[k] * ld1<BF16>(W_out, (size_t)tid * DI + k);
        es[tid] = s;
    }
    __syncthreads();
    if (tid < 128) {
        float s = ld1<BF16>(b_fc, tid);
        #pragma unroll 8
        for (int k = 0; k < DM; ++k) s += es[k] * ld1<BF16>(W_fc, (size_t)tid * DM + k);
        float th = tanhf(s);
        float xv = th > 0.f ? th : expm1f(th);
        xs[tid] = xv;
        st1<BF16>(out, (size_t)b * 128 + tid, xv);
    }
    __syncthreads();
    for (int j = tid; j < 512; j += 256) {
        int o = j & 255;
        bool is_mu = (j < 256);
        const void* w = is_mu ? W_mu : W_sig;
        float s = ld1<BF16>(is_mu ? b_mu : b_sig, o);
        #pragma unroll 8
        for (int k = 0; k < 128; ++k) s += xs[k] * ld1<BF16>(w, (size_t)o * 128 + k);
        if (is_mu) {
            st1<BF16>(out, 8192 + (size_t)b * 256 + o, s);
        } else {
            float e = s > 0.f ? s : expm1f(s);
            st1<BF16>(out, 8192 + 16384 + (size_t)b * 256 + o, e + 1.f + 1e-14f);
        }
    }
}

__global__ __launch_bounds__(256) void heads_k(
        const void* W_out, const void* W_fc, const void* b_fc,
        const void* W_mu, const void* b_mu, const void* W_sig, const void* b_sig,
        const void* A_log, const float* ysg, void* out) {
    __shared__ float yb[128];
    __shared__ float es[64];
    __shared__ float xs[128];
    if (((const u32*)A_log)[0] != 0u)
        heads_body<true >(W_out, W_fc, b_fc, W_mu, b_mu, W_sig, b_sig, ysg, out, yb, es, xs);
    else
        heads_body<false>(W_out, W_fc, b_fc, W_mu, b_mu, W_sig, b_sig, ysg, out, yb, es, xs);
}

extern "C" void kernel_launch(void* const* d_in, const int* in_sizes, int n_in,
                              void* d_out, int out_size, void* d_ws, size_t ws_size,
                              hipStream_t stream) {
    (void)in_sizes; (void)n_in; (void)ws_size; (void)out_size;
    char* ws = (char*)d_ws;
    u16*    zws = (u16*)(ws + ZWS_OFF);
    u16*    wp  = (u16*)(ws + WP_OFF);
    float4* psg = (float4*)(ws + PSG_OFF);
    float*  BCg = (float*)(ws + BC_OFF);
    float*  ysg = (float*)(ws + YS_OFF);

    // 0) pack W_enc into aligned MFMA panels
    pack_wenc<<<184, 256, 0, stream>>>(d_in[1], d_in[9], wp);
    // 1) encoder GEMM: 1024 blocks x 4 waves, coalesced LDS-staged A
    enc_gemm<<<1024, 256, 0, stream>>>(d_in[0], d_in[2], d_in[9], wp, zws);
    // 2) parallel prep over (batch, chunk)
    prep<<<512, 256, 0, stream>>>(d_in[3], d_in[4], d_in[5], d_in[6], d_in[7],
                                  d_in[8], d_in[10], d_in[9], zws, psg, BCg);
    // 3) selective scan, one thread per (d, n) chain
    scan_k<<<256, 512, 0, stream>>>(d_in[9], psg, BCg, ysg);
    // 4) heads
    heads_k<<<64, 256, 0, stream>>>(d_in[11], d_in[12], d_in[13], d_in[14],
                                    d_in[15], d_in[16], d_in[17], d_in[9], ysg, d_out);
}

// Round 4
// 635.288 us; speedup vs baseline: 2.6365x; 1.0110x over previous
//
#include <hip/hip_runtime.h>

typedef unsigned short u16;
typedef unsigned int   u32;

#define BB   64
#define TT   256
#define DIN  5881
#define DM   64
#define DI   128
#define NST  16
#define DTR  4
#define TCH  32      // timestep chunk
#define NCH  8       // chunks per batch

#define NROW (BB*TT)              // 16384 rows of the encoder GEMM
#define NKT  92                   // K-tiles of 64 (92*64 = 5888 >= 5881)
#define KQRT 23                   // K-split quarter (in tiles): 4*23 = 92

// ---- workspace layout (bytes) ----
// [0, 2MB)      zws  bf16 [16384][64]   encoder output (biased)
// [2MB, 3MB)    wp   packed W_enc panels (736 KB)
// [3MB, 35MB)   psg  f32x4 [16384][128] {dt, dt*xc, silu(g), D*xc*silu(g)}
// [35MB, 37MB)  BCg  f32 [16384][32]    {B[16], C[16]}
// [37MB, ...)   ysg  f32 [64][128]      scan output (sum over t,n)
#define ZWS_OFF  ((size_t)0)
#define WP_OFF   ((size_t)2*1024*1024)
#define PSG_OFF  ((size_t)3*1024*1024)
#define BC_OFF   ((size_t)35*1024*1024)
#define YS_OFF   ((size_t)37*1024*1024)

__device__ __forceinline__ float bf2f(u16 u) {
    union { u32 i; float f; } v; v.i = ((u32)u) << 16; return v.f;
}
__device__ __forceinline__ u16 f2bf(float f) {
    union { float f; u32 i; } v; v.f = f;
    u32 x = v.i;
    return (u16)((x + 0x7FFFu + ((x >> 16) & 1u)) >> 16);
}

typedef __attribute__((ext_vector_type(8))) short short8;
typedef __attribute__((ext_vector_type(4))) float floatx4;

template<bool BF16>
__device__ __forceinline__ float ld1(const void* p, size_t i) {
    if (BF16) return bf2f(((const u16*)p)[i]);
    else      return ((const float*)p)[i];
}
template<bool BF16>
__device__ __forceinline__ u16 ldb(const void* p, size_t i) {
    if (BF16) return ((const u16*)p)[i];
    else      return f2bf(((const float*)p)[i]);
}
template<bool BF16>
__device__ __forceinline__ void st1(void* p, size_t i, float v) {
    if (BF16) ((u16*)p)[i] = f2bf(v);
    else      ((float*)p)[i] = v;
}

__device__ __forceinline__ short8 as_s8(uint4 v) {
    union { uint4 u; short8 s; } c; c.u = v; return c.s;
}

// ============================================================================
// Kernel 0: pack W_enc into MFMA B-fragment panels (aligned, K-tail zeroed).
// ============================================================================
template<bool BF16>
__device__ __forceinline__ void pack_body(const void* Wenc, u16* wp) {
    int g = blockIdx.x * 256 + threadIdx.x;
    if (g >= NKT * 8 * 64) return;
    int lane = g & 63;  int p = g >> 6;
    int kt = p & 1, nt = (p >> 1) & 3, it = p >> 3;
    int r16 = lane & 15, quad = lane >> 4;
    int n  = nt * 16 + r16;
    int k0 = it * 64 + kt * 32 + quad * 8;
    u32 w[4];
    #pragma unroll
    for (int j = 0; j < 4; ++j) {
        int ka = k0 + 2 * j;
        u32 lo = (ka     < DIN) ? (u32)ldb<BF16>(Wenc, (size_t)n * DIN + ka)     : 0u;
        u32 hi = (ka + 1 < DIN) ? (u32)ldb<BF16>(Wenc, (size_t)n * DIN + ka + 1) : 0u;
        w[j] = lo | (hi << 16);
    }
    *(uint4*)(wp + ((size_t)p * 64 + lane) * 8) = make_uint4(w[0], w[1], w[2], w[3]);
}

__global__ __launch_bounds__(256) void pack_wenc(const void* Wenc, const void* A_log, u16* wp) {
    if (((const u32*)A_log)[0] != 0u) pack_body<true >(Wenc, wp);
    else                              pack_body<false>(Wenc, wp);
}

// ============================================================================
// Kernel 1: encoder GEMM  z[16384,64] = input[16384,5881] @ W_enc^T + b_enc
// 1024 blocks x 4 waves. Block = one 16-row M-tile; waves split K 4 ways
// (23 tiles each). BOTH operands prefetched in ping-pong named registers:
//   A: 16 coalesced u16 row-loads (lane l = element l of row j, one 128B line)
//   B: 8 dwordx4 from packed wp panels
// so every MFMA wait is a counted vmcnt(24)/vmcnt(8) with a full next tile in
// flight -- never a vmcnt(0) drain (round-3's per-tile stall). A transposed
// through a wave-private LDS tile (stride 72); single-buffered, in-order DS.
// f32 4-way LDS reduce + bias at the end.
// ============================================================================
template<bool BF16>
__device__ __forceinline__ void enc_loadr(const void* inp, int m0, int it, int lane,
                                          u16 (&rg)[16]) {
    const size_t kb = (size_t)it * 64 + lane;
    if (it != NKT - 1) {
        #pragma unroll
        for (int j = 0; j < 16; ++j)
            rg[j] = ldb<BF16>(inp, (size_t)(m0 + j) * DIN + kb);
    } else {
        bool ok = kb < DIN;
        #pragma unroll
        for (int j = 0; j < 16; ++j)
            rg[j] = ok ? ldb<BF16>(inp, (size_t)(m0 + j) * DIN + kb) : (u16)0;
    }
}

__device__ __forceinline__ void enc_loadw(const uint4* wp4, int it, int lane,
                                          uint4 (&b)[8]) {
    const uint4* p = wp4 + (size_t)it * 512 + lane;
    #pragma unroll
    for (int j = 0; j < 8; ++j) b[j] = p[j * 64];   // j = nt*2 + kt
}

__device__ __forceinline__ void enc_write(u16* ms, int lane, const u16 (&rg)[16]) {
    #pragma unroll
    for (int j = 0; j < 16; ++j) ms[j * 72 + lane] = rg[j];
}

__device__ __forceinline__ void enc_compute(const u16* ms, int r16, int quad,
                                            const uint4 (&b)[8], floatx4 (&acc)[4]) {
    short8 a0 = *(const short8*)(ms + r16 * 72 +  0 + quad * 8);
    short8 a1 = *(const short8*)(ms + r16 * 72 + 32 + quad * 8);
    #pragma unroll
    for (int nt = 0; nt < 4; ++nt) {
        acc[nt] = __builtin_amdgcn_mfma_f32_16x16x32_bf16(a0, as_s8(b[nt * 2 + 0]), acc[nt], 0, 0, 0);
        acc[nt] = __builtin_amdgcn_mfma_f32_16x16x32_bf16(a1, as_s8(b[nt * 2 + 1]), acc[nt], 0, 0, 0);
    }
}

template<bool BF16>
__device__ __forceinline__ void enc_body(const void* inp, const void* benc,
                                         const u16* wp, u16* z,
                                         u16* stg, float* zred) {
    const int tid  = threadIdx.x;
    const int wave = tid >> 6, lane = tid & 63;
    const int r16  = lane & 15, quad = lane >> 4;
    const int m0   = blockIdx.x * 16;
    const uint4* wp4 = (const uint4*)wp;
    u16* ms = stg + wave * (16 * 72);
    const int it0 = wave * KQRT;

    floatx4 acc[4];
    #pragma unroll
    for (int nt = 0; nt < 4; ++nt) acc[nt] = (floatx4){0, 0, 0, 0};

    u16   rgA[16], rgB[16];
    uint4 bA[8],  bB[8];
    enc_loadr<BF16>(inp, m0, it0, lane, rgA);
    enc_loadw(wp4, it0, lane, bA);
    int it = it0;
    #pragma unroll 1
    for (int p = 0; p < (KQRT - 1) / 2; ++p, it += 2) {
        enc_write(ms, lane, rgA);                    // waits rgA only (bA stays in flight)
        enc_loadr<BF16>(inp, m0, it + 1, lane, rgB); // issue next tile before compute
        enc_loadw(wp4, it + 1, lane, bB);
        enc_compute(ms, r16, quad, bA, acc);         // waits bA: vmcnt(24) counted
        enc_write(ms, lane, rgB);
        enc_loadr<BF16>(inp, m0, it + 2, lane, rgA);
        enc_loadw(wp4, it + 2, lane, bA);
        enc_compute(ms, r16, quad, bB, acc);
    }
    // epilogue tile: it == it0 + 22 (already loaded into rgA/bA)
    enc_write(ms, lane, rgA);
    enc_compute(ms, r16, quad, bA, acc);

    // ---- 4-way f32 reduce + bias ----
    #pragma unroll
    for (int nt = 0; nt < 4; ++nt) {
        int col = nt * 16 + r16;
        #pragma unroll
        for (int reg = 0; reg < 4; ++reg) {
            int row = quad * 4 + reg;
            zred[wave * 1024 + row * 64 + col] = acc[nt][reg];
        }
    }
    __syncthreads();
    #pragma unroll
    for (int rep = 0; rep < 4; ++rep) {
        int o = rep * 256 + tid;           // o = row*64 + col
        int col = o & 63;
        float s = zred[o] + zred[1024 + o] + zred[2048 + o] + zred[3072 + o]
                + ld1<BF16>(benc, col);
        z[(size_t)(m0 + (o >> 6)) * DM + col] = f2bf(s);
    }
}

__global__ __launch_bounds__(256, 3) void enc_gemm(const void* inp, const void* benc,
                                                   const void* A_log, const u16* wp, u16* z) {
    __shared__ __align__(16) u16   stg[4 * 16 * 72];   // 9216 B
    __shared__ __align__(16) float zred[4 * 1024];     // 16384 B
    if (((const u32*)A_log)[0] != 0u) enc_body<true >(inp, benc, wp, z, stg, zred);
    else                              enc_body<false>(inp, benc, wp, z, stg, zred);
}

// ============================================================================
// Kernel 2: prep — parallel over (batch, chunk). 512 blocks x 256 threads.
// Recomputes the 3-row conv halo (16-row halo tile) from z so chunks are
// independent. Emits per-(t,d) float4 {dt, dt*xc, silu(g), D*xc*silu(g)}
// and per-(t) B/C (f32) to workspace.
// ============================================================================
template<bool BF16>
__device__ __forceinline__ void prep_body(
        const void* W_in, const void* conv_w, const void* conv_b,
        const void* W_x, const void* W_dt, const void* b_dt, const void* D_skip,
        const u16* zws, float4* psg, float* BCg,
        u16* zc, u16* xl, u16* gl, u16* xcb, float* xd2) {

    const int bid  = blockIdx.x;
    const int b    = bid >> 3, c = bid & 7;
    const int tid  = threadIdx.x;
    const int wave = tid >> 6, lane = tid & 63;
    const int quad = lane >> 4, r16 = lane & 15;
    const int dd   = tid & 127;

    float cw[4], cb, wdt[4], bdt, Dv;
    #pragma unroll
    for (int k = 0; k < 4; ++k) cw[k] = ld1<BF16>(conv_w, dd * 4 + k);
    cb = ld1<BF16>(conv_b, dd);
    #pragma unroll
    for (int r = 0; r < 4; ++r) wdt[r] = ld1<BF16>(W_dt, dd * 4 + r);
    bdt = ld1<BF16>(b_dt, dd);
    Dv  = ld1<BF16>(D_skip, dd);

    // xz B-frags: W_in rows (wave*64 + nt*16 + r16), K=64 (2 k-tiles)
    short8 win[4][2];
    #pragma unroll
    for (int nt = 0; nt < 4; ++nt)
        #pragma unroll
        for (int kt = 0; kt < 2; ++kt) {
            size_t base = (size_t)(wave * 64 + nt * 16 + r16) * DM + kt * 32 + quad * 8;
            short8 v;
            #pragma unroll
            for (int e = 0; e < 8; ++e) v[e] = (short)ldb<BF16>(W_in, base + e);
            win[nt][kt] = v;
        }

    // xdbl B-frags: W_x rows j = wave*16 + r16 (waves 0..2), K=128 (4 k-tiles)
    short8 wx[4];
    {
        int j = wave * 16 + r16;
        #pragma unroll
        for (int kt = 0; kt < 4; ++kt) {
            short8 v = (short8){0,0,0,0,0,0,0,0};
            if (wave < 3 && j < DTR + 2 * NST) {
                size_t base = (size_t)j * DI + kt * 32 + quad * 8;
                #pragma unroll
                for (int e = 0; e < 8; ++e) v[e] = (short)ldb<BF16>(W_x, base + e);
            }
            wx[kt] = v;
        }
    }

    // ---- stage z: 48 rows covering t in [c*32-16, c*32+32), t<0 -> 0 ----
    const int base_t = c * 32 - 16;
    for (int i = tid; i < 48 * 64; i += 256) {
        int rr = i >> 6, nn = i & 63, t = base_t + rr;
        u16 v = 0;
        if (t >= 0) v = zws[(size_t)(b * TT + t) * DM + nn];
        zc[rr * 72 + nn] = v;
    }
    __syncthreads();

    // ---- xz = z @ W_in^T (MFMA, 3 m-tiles); x rows rr>=13, gate rr>=16 ----
    floatx4 xza[3][4];
    #pragma unroll
    for (int mt = 0; mt < 3; ++mt)
        #pragma unroll
        for (int nt = 0; nt < 4; ++nt) xza[mt][nt] = (floatx4){0,0,0,0};
    #pragma unroll
    for (int kt = 0; kt < 2; ++kt) {
        short8 a[3];
        #pragma unroll
        for (int mt = 0; mt < 3; ++mt)
            a[mt] = *(const short8*)(&zc[(mt * 16 + r16) * 72 + kt * 32 + quad * 8]);
        #pragma unroll
        for (int nt = 0; nt < 4; ++nt)
            #pragma unroll
            for (int mt = 0; mt < 3; ++mt)
                xza[mt][nt] = __builtin_amdgcn_mfma_f32_16x16x32_bf16(a[mt], win[nt][kt], xza[mt][nt], 0, 0, 0);
    }
    #pragma unroll
    for (int mt = 0; mt < 3; ++mt)
        #pragma unroll
        for (int nt = 0; nt < 4; ++nt) {
            int n = wave * 64 + nt * 16 + r16;
            #pragma unroll
            for (int reg = 0; reg < 4; ++reg) {
                int rr = mt * 16 + quad * 4 + reg;
                u16 v = f2bf(xza[mt][nt][reg]);
                if (n < DI) { if (rr >= 13) xl[(rr - 13) * 128 + n] = v; }
                else if (rr >= 16) gl[(rr - 16) * 128 + (n - DI)] = v;
            }
        }
    __syncthreads();

    // ---- causal conv + SiLU -> xcb ----
    for (int it2 = tid; it2 < TCH * DI; it2 += 256) {
        int t = it2 >> 7, d = it2 & 127;
        float a = cb;
        #pragma unroll
        for (int k = 0; k < 4; ++k) a += bf2f(xl[(t + k) * 128 + d]) * cw[k];
        float s = a / (1.f + expf(-a));
        xcb[t * 136 + d] = f2bf(s);
    }
    __syncthreads();

    // ---- x_dbl = xconv @ W_x^T (MFMA, waves 0..2) ----
    {
        floatx4 xda0 = (floatx4){0,0,0,0}, xda1 = (floatx4){0,0,0,0};
        if (wave < 3) {
            #pragma unroll
            for (int kt = 0; kt < 4; ++kt) {
                short8 a0 = *(const short8*)(&xcb[(0 * 16 + r16) * 136 + kt * 32 + quad * 8]);
                short8 a1 = *(const short8*)(&xcb[(1 * 16 + r16) * 136 + kt * 32 + quad * 8]);
                xda0 = __builtin_amdgcn_mfma_f32_16x16x32_bf16(a0, wx[kt], xda0, 0, 0, 0);
                xda1 = __builtin_amdgcn_mfma_f32_16x16x32_bf16(a1, wx[kt], xda1, 0, 0, 0);
            }
            int j = wave * 16 + r16;
            if (j < DTR + 2 * NST) {
                #pragma unroll
                for (int reg = 0; reg < 4; ++reg) {
                    xd2[(0 * 16 + quad * 4 + reg) * 40 + j] = xda0[reg];
                    xd2[(1 * 16 + quad * 4 + reg) * 40 + j] = xda1[reg];
                }
            }
        }
    }
    __syncthreads();

    // ---- pointwise finalize: dt (f32), dx, sg, skip; write psg + BC ----
    const size_t rowb = (size_t)b * TT + c * 32;
    for (int it2 = tid; it2 < TCH * DI; it2 += 256) {
        int t = it2 >> 7, d = it2 & 127;
        float v = bdt;
        #pragma unroll
        for (int r = 0; r < 4; ++r) v += xd2[t * 40 + r] * wdt[r];
        float sp  = (v > 20.f) ? v : log1pf(expf(v));
        float xcv = bf2f(xcb[t * 136 + d]);
        float g   = bf2f(gl[t * 128 + d]);
        float sg  = g / (1.f + expf(-g));
        psg[(rowb + t) * DI + d] = make_float4(sp, sp * xcv, sg, Dv * xcv * sg);
    }
    for (int i = tid; i < TCH * 32; i += 256) {
        int t = i >> 5, j = i & 31;
        BCg[(rowb + t) * 32 + j] = xd2[t * 40 + DTR + j];
    }
}

__global__ __launch_bounds__(256) void prep(
        const void* W_in, const void* conv_w, const void* conv_b,
        const void* W_x, const void* W_dt, const void* b_dt, const void* D_skip,
        const void* A_log, const u16* zws, float4* psg, float* BCg) {
    __shared__ __align__(16) u16  zc[48 * 72];
    __shared__ __align__(16) u16  xl[35 * 128];
    __shared__ __align__(16) u16  gl[32 * 128];
    __shared__ __align__(16) u16  xcb[32 * 136];
    __shared__ __align__(16) float xd2[32 * 40];
    if (((const u32*)A_log)[0] != 0u)
        prep_body<true >(W_in, conv_w, conv_b, W_x, W_dt, b_dt, D_skip, zws, psg, BCg,
                         zc, xl, gl, xcb, xd2);
    else
        prep_body<false>(W_in, conv_w, conv_b, W_x, W_dt, b_dt, D_skip, zws, psg, BCg,
                         zc, xl, gl, xcb, xd2);
}

// ============================================================================
// Kernel 3: selective scan. 256 blocks = (b, d-quarter), 512 threads:
// one thread per (d, n) chain. No LDS; register ping-pong prefetch (static
// indices only). n-reduction deferred to end via sg-scaled partials.
// ============================================================================
__device__ __forceinline__ void scan_ld(const float4* psg, const float* BCg,
        size_t pbase, size_t bbase, int s, float4 (&P)[8], float (&Bv)[8], float (&Cv)[8]) {
    #pragma unroll
    for (int q = 0; q < 8; ++q) {
        int r = s * 8 + q;
        P[q]  = psg[pbase + (size_t)r * DI];
        Bv[q] = BCg[bbase + (size_t)r * 32];
        Cv[q] = BCg[bbase + (size_t)r * 32 + 16];
    }
}
__device__ __forceinline__ void scan_cmp(const float4 (&P)[8], const float (&Bv)[8],
        const float (&Cv)[8], float Av, int n, float& h, float& acc, float& sk) {
    #pragma unroll
    for (int q = 0; q < 8; ++q) {
        float e = expf(P[q].x * Av);
        h   = fmaf(e, h, P[q].y * Bv[q]);
        acc = fmaf(h * Cv[q], P[q].z, acc);
        sk += (n == 0) ? P[q].w : 0.f;
    }
}

__global__ __launch_bounds__(512) void scan_k(const void* A_log, const float4* psg,
        const float* BCg, float* ysg) {
    const int tid = threadIdx.x;
    const int b = blockIdx.x >> 2, dq = blockIdx.x & 3;
    const int dl = tid >> 4, n = tid & 15;
    const int d = dq * 32 + dl;
    const bool isbf = (((const u32*)A_log)[0] != 0u);
    float al = isbf ? bf2f(((const u16*)A_log)[d * NST + n])
                    : ((const float*)A_log)[d * NST + n];
    const float Av = -expf(al);
    const size_t rb = (size_t)b * TT;
    const size_t pbase = rb * DI + d;
    const size_t bbase = rb * 32 + n;

    float4 pA[8], pB[8];
    float  BA[8], CA[8], Bb[8], Cb[8];
    float h = 0.f, acc = 0.f, sk = 0.f;

    scan_ld(psg, BCg, pbase, bbase, 0, pA, BA, CA);
    for (int s = 0; s < 32; s += 2) {
        scan_ld(psg, BCg, pbase, bbase, s + 1, pB, Bb, Cb);
        scan_cmp(pA, BA, CA, Av, n, h, acc, sk);
        if (s + 2 < 32) scan_ld(psg, BCg, pbase, bbase, s + 2, pA, BA, CA);
        scan_cmp(pB, Bb, Cb, Av, n, h, acc, sk);
    }
    acc += __shfl_xor(acc, 1);
    acc += __shfl_xor(acc, 2);
    acc += __shfl_xor(acc, 4);
    acc += __shfl_xor(acc, 8);
    if (n == 0) ysg[(size_t)b * DI + d] = acc + sk;
}

// ============================================================================
// Kernel 4: heads. 64 blocks x 256 threads.
// ============================================================================
template<bool BF16>
__device__ __forceinline__ void heads_body(
        const void* W_out, const void* W_fc, const void* b_fc,
        const void* W_mu, const void* b_mu, const void* W_sig, const void* b_sig,
        const float* ysg, void* out, float* yb, float* es, float* xs) {
    const int b = blockIdx.x, tid = threadIdx.x;
    if (tid < DI) yb[tid] = ysg[(size_t)b * DI + tid] * (1.f / (float)TT);
    __syncthreads();
    if (tid < DM) {
        float s = 0.f;
        #pragma unroll 8
        for (int k = 0; k < DI; ++k) s += yb[k] * ld1<BF16>(W_out, (size_t)tid * DI + k);
        es[tid] = s;
    }
    __syncthreads();
    if (tid < 128) {
        float s = ld1<BF16>(b_fc, tid);
        #pragma unroll 8
        for (int k = 0; k < DM; ++k) s += es[k] * ld1<BF16>(W_fc, (size_t)tid * DM + k);
        float th = tanhf(s);
        float xv = th > 0.f ? th : expm1f(th);
        xs[tid] = xv;
        st1<BF16>(out, (size_t)b * 128 + tid, xv);
    }
    __syncthreads();
    for (int j = tid; j < 512; j += 256) {
        int o = j & 255;
        bool is_mu = (j < 256);
        const void* w = is_mu ? W_mu : W_sig;
        float s = ld1<BF16>(is_mu ? b_mu : b_sig, o);
        #pragma unroll 8
        for (int k = 0; k < 128; ++k) s += xs[k] * ld1<BF16>(w, (size_t)o * 128 + k);
        if (is_mu) {
            st1<BF16>(out, 8192 + (size_t)b * 256 + o, s);
        } else {
            float e = s > 0.f ? s : expm1f(s);
            st1<BF16>(out, 8192 + 16384 + (size_t)b * 256 + o, e + 1.f + 1e-14f);
        }
    }
}

__global__ __launch_bounds__(256) void heads_k(
        const void* W_out, const void* W_fc, const void* b_fc,
        const void* W_mu, const void* b_mu, const void* W_sig, const void* b_sig,
        const void* A_log, const float* ysg, void* out) {
    __shared__ float yb[128];
    __shared__ float es[64];
    __shared__ float xs[128];
    if (((const u32*)A_log)[0] != 0u)
        heads_body<true >(W_out, W_fc, b_fc, W_mu, b_mu, W_sig, b_sig, ysg, out, yb, es, xs);
    else
        heads_body<false>(W_out, W_fc, b_fc, W_mu, b_mu, W_sig, b_sig, ysg, out, yb, es, xs);
}

extern "C" void kernel_launch(void* const* d_in, const int* in_sizes, int n_in,
                              void* d_out, int out_size, void* d_ws, size_t ws_size,
                              hipStream_t stream) {
    (void)in_sizes; (void)n_in; (void)ws_size; (void)out_size;
    char* ws = (char*)d_ws;
    u16*    zws = (u16*)(ws + ZWS_OFF);
    u16*    wp  = (u16*)(ws + WP_OFF);
    float4* psg = (float4*)(ws + PSG_OFF);
    float*  BCg = (float*)(ws + BC_OFF);
    float*  ysg = (float*)(ws + YS_OFF);

    // 0) pack W_enc into aligned MFMA panels
    pack_wenc<<<184, 256, 0, stream>>>(d_in[1], d_in[9], wp);
    // 1) encoder GEMM: 1024 blocks x 4 waves, coalesced LDS-staged A +
    //    double-prefetched (A,B) registers, counted vmcnt only
    enc_gemm<<<1024, 256, 0, stream>>>(d_in[0], d_in[2], d_in[9], wp, zws);
    // 2) parallel prep over (batch, chunk)
    prep<<<512, 256, 0, stream>>>(d_in[3], d_in[4], d_in[5], d_in[6], d_in[7],
                                  d_in[8], d_in[10], d_in[9], zws, psg, BCg);
    // 3) selective scan, one thread per (d, n) chain
    scan_k<<<256, 512, 0, stream>>>(d_in[9], psg, BCg, ysg);
    // 4) heads
    heads_k<<<64, 256, 0, stream>>>(d_in[11], d_in[12], d_in[13], d_in[14],
                                    d_in[15], d_in[16], d_in[17], d_in[9], ysg, d_out);
}

// Round 5
// 631.884 us; speedup vs baseline: 2.6507x; 1.0054x over previous
//
#include <hip/hip_runtime.h>

typedef unsigned short u16;
typedef unsigned int   u32;

#define BB   64
#define TT   256
#define DIN  5881
#define DM   64
#define DI   128
#define NST  16
#define DTR  4
#define TCH  32      // timestep chunk
#define NCH  8       // chunks per batch

#define NROW (BB*TT)              // 16384 rows of the encoder GEMM
#define NKT  92                   // K-tiles of 64 (92*64 = 5888 >= 5881)
#define KQRT 23                   // K-split quarter (in tiles): 4*23 = 92
#define MRT  32                   // M-rows per block (amortizes B-panel reads)

// ---- workspace layout (bytes) ----
// [0, 2MB)      zws  bf16 [16384][64]   encoder output (biased)
// [2MB, 3MB)    wp   packed W_enc panels (736 KB)
// [3MB, 35MB)   psg  f32x4 [16384][128] {dt, dt*xc, silu(g), D*xc*silu(g)}
// [35MB, 37MB)  BCg  f32 [16384][32]    {B[16], C[16]}
// [37MB, ...)   ysg  f32 [64][128]      scan output (sum over t,n)
#define ZWS_OFF  ((size_t)0)
#define WP_OFF   ((size_t)2*1024*1024)
#define PSG_OFF  ((size_t)3*1024*1024)
#define BC_OFF   ((size_t)35*1024*1024)
#define YS_OFF   ((size_t)37*1024*1024)

__device__ __forceinline__ float bf2f(u16 u) {
    union { u32 i; float f; } v; v.i = ((u32)u) << 16; return v.f;
}
__device__ __forceinline__ u16 f2bf(float f) {
    union { float f; u32 i; } v; v.f = f;
    u32 x = v.i;
    return (u16)((x + 0x7FFFu + ((x >> 16) & 1u)) >> 16);
}

typedef __attribute__((ext_vector_type(8))) short short8;
typedef __attribute__((ext_vector_type(4))) float floatx4;

template<bool BF16>
__device__ __forceinline__ float ld1(const void* p, size_t i) {
    if (BF16) return bf2f(((const u16*)p)[i]);
    else      return ((const float*)p)[i];
}
template<bool BF16>
__device__ __forceinline__ u16 ldb(const void* p, size_t i) {
    if (BF16) return ((const u16*)p)[i];
    else      return f2bf(((const float*)p)[i]);
}
template<bool BF16>
__device__ __forceinline__ void st1(void* p, size_t i, float v) {
    if (BF16) ((u16*)p)[i] = f2bf(v);
    else      ((float*)p)[i] = v;
}

__device__ __forceinline__ short8 as_s8(uint4 v) {
    union { uint4 u; short8 s; } c; c.u = v; return c.s;
}

// ============================================================================
// Kernel 0: pack W_enc into MFMA B-fragment panels (aligned, K-tail zeroed).
// ============================================================================
template<bool BF16>
__device__ __forceinline__ void pack_body(const void* Wenc, u16* wp) {
    int g = blockIdx.x * 256 + threadIdx.x;
    if (g >= NKT * 8 * 64) return;
    int lane = g & 63;  int p = g >> 6;
    int kt = p & 1, nt = (p >> 1) & 3, it = p >> 3;
    int r16 = lane & 15, quad = lane >> 4;
    int n  = nt * 16 + r16;
    int k0 = it * 64 + kt * 32 + quad * 8;
    u32 w[4];
    #pragma unroll
    for (int j = 0; j < 4; ++j) {
        int ka = k0 + 2 * j;
        u32 lo = (ka     < DIN) ? (u32)ldb<BF16>(Wenc, (size_t)n * DIN + ka)     : 0u;
        u32 hi = (ka + 1 < DIN) ? (u32)ldb<BF16>(Wenc, (size_t)n * DIN + ka + 1) : 0u;
        w[j] = lo | (hi << 16);
    }
    *(uint4*)(wp + ((size_t)p * 64 + lane) * 8) = make_uint4(w[0], w[1], w[2], w[3]);
}

__global__ __launch_bounds__(256) void pack_wenc(const void* Wenc, const void* A_log, u16* wp) {
    if (((const u32*)A_log)[0] != 0u) pack_body<true >(Wenc, wp);
    else                              pack_body<false>(Wenc, wp);
}

// ============================================================================
// Kernel 1: encoder GEMM  z[16384,64] = input[16384,5881] @ W_enc^T + b_enc
// 512 blocks x 4 waves. Block = one 32-row M-tile (2 MFMA m-tiles); waves
// split K 4 ways (23 tiles each). 32-row tile amortizes B-panel traffic 2x
// vs round-4's 16-row tile (B re-read 754 MB -> 377 MB; total vector-memory
// volume 950 -> 570 MB -- the measured 6.2 TB/s traffic wall was the limit).
// Single-buffered rgA/bA with counted-wait issue order:
//   ds_write(rgA cur) [waits rgA, bA in flight] -> issue rgA(next)
//   -> compute(bA cur) [waits bA, rgA(next) in flight] -> issue bA(next)
// f32 4-way LDS reduce + bias at the end.
// ============================================================================
template<bool BF16>
__device__ __forceinline__ void enc_loadr32(const void* inp, int m0, int it, int lane,
                                            u16 (&rg)[MRT]) {
    const size_t kb = (size_t)it * 64 + lane;
    if (it != NKT - 1) {
        #pragma unroll
        for (int j = 0; j < MRT; ++j)
            rg[j] = ldb<BF16>(inp, (size_t)(m0 + j) * DIN + kb);
    } else {
        bool ok = kb < DIN;
        #pragma unroll
        for (int j = 0; j < MRT; ++j)
            rg[j] = ok ? ldb<BF16>(inp, (size_t)(m0 + j) * DIN + kb) : (u16)0;
    }
}

__device__ __forceinline__ void enc_loadw(const uint4* wp4, int it, int lane,
                                          uint4 (&b)[8]) {
    const uint4* p = wp4 + (size_t)it * 512 + lane;
    #pragma unroll
    for (int j = 0; j < 8; ++j) b[j] = p[j * 64];   // j = nt*2 + kt
}

__device__ __forceinline__ void enc_write32(u16* ms, int lane, const u16 (&rg)[MRT]) {
    #pragma unroll
    for (int j = 0; j < MRT; ++j) ms[j * 72 + lane] = rg[j];
}

__device__ __forceinline__ void enc_compute2(const u16* ms, int r16, int quad,
                                             const uint4 (&b)[8], floatx4 (&acc)[2][4]) {
    #pragma unroll
    for (int mt = 0; mt < 2; ++mt) {
        short8 a0 = *(const short8*)(ms + (mt * 16 + r16) * 72 +  0 + quad * 8);
        short8 a1 = *(const short8*)(ms + (mt * 16 + r16) * 72 + 32 + quad * 8);
        #pragma unroll
        for (int nt = 0; nt < 4; ++nt) {
            acc[mt][nt] = __builtin_amdgcn_mfma_f32_16x16x32_bf16(a0, as_s8(b[nt * 2 + 0]), acc[mt][nt], 0, 0, 0);
            acc[mt][nt] = __builtin_amdgcn_mfma_f32_16x16x32_bf16(a1, as_s8(b[nt * 2 + 1]), acc[mt][nt], 0, 0, 0);
        }
    }
}

template<bool BF16>
__device__ __forceinline__ void enc_body(const void* inp, const void* benc,
                                         const u16* wp, u16* z,
                                         u16* stg, float* zred) {
    const int tid  = threadIdx.x;
    const int wave = tid >> 6, lane = tid & 63;
    const int r16  = lane & 15, quad = lane >> 4;
    const int m0   = blockIdx.x * MRT;
    const uint4* wp4 = (const uint4*)wp;
    u16* ms = stg + wave * (MRT * 72);
    const int it0 = wave * KQRT;

    floatx4 acc[2][4];
    #pragma unroll
    for (int mt = 0; mt < 2; ++mt)
        #pragma unroll
        for (int nt = 0; nt < 4; ++nt) acc[mt][nt] = (floatx4){0, 0, 0, 0};

    u16   rgA[MRT];
    uint4 bA[8];
    enc_loadr32<BF16>(inp, m0, it0, lane, rgA);
    enc_loadw(wp4, it0, lane, bA);
    #pragma unroll 1
    for (int p = 0; p < KQRT; ++p) {
        const int it = it0 + p;
        enc_write32(ms, lane, rgA);               // waits rgA (bA stays in flight)
        if (p + 1 < KQRT)
            enc_loadr32<BF16>(inp, m0, it + 1, lane, rgA);
        enc_compute2(ms, r16, quad, bA, acc);     // waits bA (rgA-next in flight)
        if (p + 1 < KQRT)
            enc_loadw(wp4, it + 1, lane, bA);
    }

    // ---- 4-way f32 reduce + bias ----
    #pragma unroll
    for (int mt = 0; mt < 2; ++mt)
        #pragma unroll
        for (int nt = 0; nt < 4; ++nt) {
            int col = nt * 16 + r16;
            #pragma unroll
            for (int reg = 0; reg < 4; ++reg) {
                int row = mt * 16 + quad * 4 + reg;
                zred[wave * (MRT * 64) + row * 64 + col] = acc[mt][nt][reg];
            }
        }
    __syncthreads();
    #pragma unroll
    for (int rep = 0; rep < (MRT * 64) / 256; ++rep) {
        int o = rep * 256 + tid;           // o = row*64 + col, row in [0,32)
        int col = o & 63;
        float s = zred[o] + zred[2048 + o] + zred[4096 + o] + zred[6144 + o]
                + ld1<BF16>(benc, col);
        z[(size_t)(m0 + (o >> 6)) * DM + col] = f2bf(s);
    }
}

__global__ __launch_bounds__(256) void enc_gemm(const void* inp, const void* benc,
                                                const void* A_log, const u16* wp, u16* z) {
    __shared__ __align__(16) u16   stg[4 * MRT * 72];   // 18432 B
    __shared__ __align__(16) float zred[4 * MRT * 64];  // 32768 B
    if (((const u32*)A_log)[0] != 0u) enc_body<true >(inp, benc, wp, z, stg, zred);
    else                              enc_body<false>(inp, benc, wp, z, stg, zred);
}

// ============================================================================
// Kernel 2: prep — parallel over (batch, chunk). 512 blocks x 256 threads.
// Recomputes the 3-row conv halo (16-row halo tile) from z so chunks are
// independent. Emits per-(t,d) float4 {dt, dt*xc, silu(g), D*xc*silu(g)}
// and per-(t) B/C (f32) to workspace.
// ============================================================================
template<bool BF16>
__device__ __forceinline__ void prep_body(
        const void* W_in, const void* conv_w, const void* conv_b,
        const void* W_x, const void* W_dt, const void* b_dt, const void* D_skip,
        const u16* zws, float4* psg, float* BCg,
        u16* zc, u16* xl, u16* gl, u16* xcb, float* xd2) {

    const int bid  = blockIdx.x;
    const int b    = bid >> 3, c = bid & 7;
    const int tid  = threadIdx.x;
    const int wave = tid >> 6, lane = tid & 63;
    const int quad = lane >> 4, r16 = lane & 15;
    const int dd   = tid & 127;

    float cw[4], cb, wdt[4], bdt, Dv;
    #pragma unroll
    for (int k = 0; k < 4; ++k) cw[k] = ld1<BF16>(conv_w, dd * 4 + k);
    cb = ld1<BF16>(conv_b, dd);
    #pragma unroll
    for (int r = 0; r < 4; ++r) wdt[r] = ld1<BF16>(W_dt, dd * 4 + r);
    bdt = ld1<BF16>(b_dt, dd);
    Dv  = ld1<BF16>(D_skip, dd);

    // xz B-frags: W_in rows (wave*64 + nt*16 + r16), K=64 (2 k-tiles)
    short8 win[4][2];
    #pragma unroll
    for (int nt = 0; nt < 4; ++nt)
        #pragma unroll
        for (int kt = 0; kt < 2; ++kt) {
            size_t base = (size_t)(wave * 64 + nt * 16 + r16) * DM + kt * 32 + quad * 8;
            short8 v;
            #pragma unroll
            for (int e = 0; e < 8; ++e) v[e] = (short)ldb<BF16>(W_in, base + e);
            win[nt][kt] = v;
        }

    // xdbl B-frags: W_x rows j = wave*16 + r16 (waves 0..2), K=128 (4 k-tiles)
    short8 wx[4];
    {
        int j = wave * 16 + r16;
        #pragma unroll
        for (int kt = 0; kt < 4; ++kt) {
            short8 v = (short8){0,0,0,0,0,0,0,0};
            if (wave < 3 && j < DTR + 2 * NST) {
                size_t base = (size_t)j * DI + kt * 32 + quad * 8;
                #pragma unroll
                for (int e = 0; e < 8; ++e) v[e] = (short)ldb<BF16>(W_x, base + e);
            }
            wx[kt] = v;
        }
    }

    // ---- stage z: 48 rows covering t in [c*32-16, c*32+32), t<0 -> 0 ----
    const int base_t = c * 32 - 16;
    for (int i = tid; i < 48 * 64; i += 256) {
        int rr = i >> 6, nn = i & 63, t = base_t + rr;
        u16 v = 0;
        if (t >= 0) v = zws[(size_t)(b * TT + t) * DM + nn];
        zc[rr * 72 + nn] = v;
    }
    __syncthreads();

    // ---- xz = z @ W_in^T (MFMA, 3 m-tiles); x rows rr>=13, gate rr>=16 ----
    floatx4 xza[3][4];
    #pragma unroll
    for (int mt = 0; mt < 3; ++mt)
        #pragma unroll
        for (int nt = 0; nt < 4; ++nt) xza[mt][nt] = (floatx4){0,0,0,0};
    #pragma unroll
    for (int kt = 0; kt < 2; ++kt) {
        short8 a[3];
        #pragma unroll
        for (int mt = 0; mt < 3; ++mt)
            a[mt] = *(const short8*)(&zc[(mt * 16 + r16) * 72 + kt * 32 + quad * 8]);
        #pragma unroll
        for (int nt = 0; nt < 4; ++nt)
            #pragma unroll
            for (int mt = 0; mt < 3; ++mt)
                xza[mt][nt] = __builtin_amdgcn_mfma_f32_16x16x32_bf16(a[mt], win[nt][kt], xza[mt][nt], 0, 0, 0);
    }
    #pragma unroll
    for (int mt = 0; mt < 3; ++mt)
        #pragma unroll
        for (int nt = 0; nt < 4; ++nt) {
            int n = wave * 64 + nt * 16 + r16;
            #pragma unroll
            for (int reg = 0; reg < 4; ++reg) {
                int rr = mt * 16 + quad * 4 + reg;
                u16 v = f2bf(xza[mt][nt][reg]);
                if (n < DI) { if (rr >= 13) xl[(rr - 13) * 128 + n] = v; }
                else if (rr >= 16) gl[(rr - 16) * 128 + (n - DI)] = v;
            }
        }
    __syncthreads();

    // ---- causal conv + SiLU -> xcb ----
    for (int it2 = tid; it2 < TCH * DI; it2 += 256) {
        int t = it2 >> 7, d = it2 & 127;
        float a = cb;
        #pragma unroll
        for (int k = 0; k < 4; ++k) a += bf2f(xl[(t + k) * 128 + d]) * cw[k];
        float s = a / (1.f + expf(-a));
        xcb[t * 136 + d] = f2bf(s);
    }
    __syncthreads();

    // ---- x_dbl = xconv @ W_x^T (MFMA, waves 0..2) ----
    {
        floatx4 xda0 = (floatx4){0,0,0,0}, xda1 = (floatx4){0,0,0,0};
        if (wave < 3) {
            #pragma unroll
            for (int kt = 0; kt < 4; ++kt) {
                short8 a0 = *(const short8*)(&xcb[(0 * 16 + r16) * 136 + kt * 32 + quad * 8]);
                short8 a1 = *(const short8*)(&xcb[(1 * 16 + r16) * 136 + kt * 32 + quad * 8]);
                xda0 = __builtin_amdgcn_mfma_f32_16x16x32_bf16(a0, wx[kt], xda0, 0, 0, 0);
                xda1 = __builtin_amdgcn_mfma_f32_16x16x32_bf16(a1, wx[kt], xda1, 0, 0, 0);
            }
            int j = wave * 16 + r16;
            if (j < DTR + 2 * NST) {
                #pragma unroll
                for (int reg = 0; reg < 4; ++reg) {
                    xd2[(0 * 16 + quad * 4 + reg) * 40 + j] = xda0[reg];
                    xd2[(1 * 16 + quad * 4 + reg) * 40 + j] = xda1[reg];
                }
            }
        }
    }
    __syncthreads();

    // ---- pointwise finalize: dt (f32), dx, sg, skip; write psg + BC ----
    const size_t rowb = (size_t)b * TT + c * 32;
    for (int it2 = tid; it2 < TCH * DI; it2 += 256) {
        int t = it2 >> 7, d = it2 & 127;
        float v = bdt;
        #pragma unroll
        for (int r = 0; r < 4; ++r) v += xd2[t * 40 + r] * wdt[r];
        float sp  = (v > 20.f) ? v : log1pf(expf(v));
        float xcv = bf2f(xcb[t * 136 + d]);
        float g   = bf2f(gl[t * 128 + d]);
        float sg  = g / (1.f + expf(-g));
        psg[(rowb + t) * DI + d] = make_float4(sp, sp * xcv, sg, Dv * xcv * sg);
    }
    for (int i = tid; i < TCH * 32; i += 256) {
        int t = i >> 5, j = i & 31;
        BCg[(rowb + t) * 32 + j] = xd2[t * 40 + DTR + j];
    }
}

__global__ __launch_bounds__(256) void prep(
        const void* W_in, const void* conv_w, const void* conv_b,
        const void* W_x, const void* W_dt, const void* b_dt, const void* D_skip,
        const void* A_log, const u16* zws, float4* psg, float* BCg) {
    __shared__ __align__(16) u16  zc[48 * 72];
    __shared__ __align__(16) u16  xl[35 * 128];
    __shared__ __align__(16) u16  gl[32 * 128];
    __shared__ __align__(16) u16  xcb[32 * 136];
    __shared__ __align__(16) float xd2[32 * 40];
    if (((const u32*)A_log)[0] != 0u)
        prep_body<true >(W_in, conv_w, conv_b, W_x, W_dt, b_dt, D_skip, zws, psg, BCg,
                         zc, xl, gl, xcb, xd2);
    else
        prep_body<false>(W_in, conv_w, conv_b, W_x, W_dt, b_dt, D_skip, zws, psg, BCg,
                         zc, xl, gl, xcb, xd2);
}

// ============================================================================
// Kernel 3: selective scan. 256 blocks = (b, d-quarter), 512 threads:
// one thread per (d, n) chain. No LDS; register ping-pong prefetch (static
// indices only). n-reduction deferred to end via sg-scaled partials.
// ============================================================================
__device__ __forceinline__ void scan_ld(const float4* psg, const float* BCg,
        size_t pbase, size_t bbase, int s, float4 (&P)[8], float (&Bv)[8], float (&Cv)[8]) {
    #pragma unroll
    for (int q = 0; q < 8; ++q) {
        int r = s * 8 + q;
        P[q]  = psg[pbase + (size_t)r * DI];
        Bv[q] = BCg[bbase + (size_t)r * 32];
        Cv[q] = BCg[bbase + (size_t)r * 32 + 16];
    }
}
__device__ __forceinline__ void scan_cmp(const float4 (&P)[8], const float (&Bv)[8],
        const float (&Cv)[8], float Av, int n, float& h, float& acc, float& sk) {
    #pragma unroll
    for (int q = 0; q < 8; ++q) {
        float e = expf(P[q].x * Av);
        h   = fmaf(e, h, P[q].y * Bv[q]);
        acc = fmaf(h * Cv[q], P[q].z, acc);
        sk += (n == 0) ? P[q].w : 0.f;
    }
}

__global__ __launch_bounds__(512) void scan_k(const void* A_log, const float4* psg,
        const float* BCg, float* ysg) {
    const int tid = threadIdx.x;
    const int b = blockIdx.x >> 2, dq = blockIdx.x & 3;
    const int dl = tid >> 4, n = tid & 15;
    const int d = dq * 32 + dl;
    const bool isbf = (((const u32*)A_log)[0] != 0u);
    float al = isbf ? bf2f(((const u16*)A_log)[d * NST + n])
                    : ((const float*)A_log)[d * NST + n];
    const float Av = -expf(al);
    const size_t rb = (size_t)b * TT;
    const size_t pbase = rb * DI + d;
    const size_t bbase = rb * 32 + n;

    float4 pA[8], pB[8];
    float  BA[8], CA[8], Bb[8], Cb[8];
    float h = 0.f, acc = 0.f, sk = 0.f;

    scan_ld(psg, BCg, pbase, bbase, 0, pA, BA, CA);
    for (int s = 0; s < 32; s += 2) {
        scan_ld(psg, BCg, pbase, bbase, s + 1, pB, Bb, Cb);
        scan_cmp(pA, BA, CA, Av, n, h, acc, sk);
        if (s + 2 < 32) scan_ld(psg, BCg, pbase, bbase, s + 2, pA, BA, CA);
        scan_cmp(pB, Bb, Cb, Av, n, h, acc, sk);
    }
    acc += __shfl_xor(acc, 1);
    acc += __shfl_xor(acc, 2);
    acc += __shfl_xor(acc, 4);
    acc += __shfl_xor(acc, 8);
    if (n == 0) ysg[(size_t)b * DI + d] = acc + sk;
}

// ============================================================================
// Kernel 4: heads. 64 blocks x 256 threads.
// ============================================================================
template<bool BF16>
__device__ __forceinline__ void heads_body(
        const void* W_out, const void* W_fc, const void* b_fc,
        const void* W_mu, const void* b_mu, const void* W_sig, const void* b_sig,
        const float* ysg, void* out, float* yb, float* es, float* xs) {
    const int b = blockIdx.x, tid = threadIdx.x;
    if (tid < DI) yb[tid] = ysg[(size_t)b * DI + tid] * (1.f / (float)TT);
    __syncthreads();
    if (tid < DM) {
        float s = 0.f;
        #pragma unroll 8
        for (int k = 0; k < DI; ++k) s += yb[k] * ld1<BF16>(W_out, (size_t)tid * DI + k);
        es[tid] = s;
    }
    __syncthreads();
    if (tid < 128) {
        float s = ld1<BF16>(b_fc, tid);
        #pragma unroll 8
        for (int k = 0; k < DM; ++k) s += es[k] * ld1<BF16>(W_fc, (size_t)tid * DM + k);
        float th = tanhf(s);
        float xv = th > 0.f ? th : expm1f(th);
        xs[tid] = xv;
        st1<BF16>(out, (size_t)b * 128 + tid, xv);
    }
    __syncthreads();
    for (int j = tid; j < 512; j += 256) {
        int o = j & 255;
        bool is_mu = (j < 256);
        const void* w = is_mu ? W_mu : W_sig;
        float s = ld1<BF16>(is_mu ? b_mu : b_sig, o);
        #pragma unroll 8
        for (int k = 0; k < 128; ++k) s += xs[k] * ld1<BF16>(w, (size_t)o * 128 + k);
        if (is_mu) {
            st1<BF16>(out, 8192 + (size_t)b * 256 + o, s);
        } else {
            float e = s > 0.f ? s : expm1f(s);
            st1<BF16>(out, 8192 + 16384 + (size_t)b * 256 + o, e + 1.f + 1e-14f);
        }
    }
}

__global__ __launch_bounds__(256) void heads_k(
        const void* W_out, const void* W_fc, const void* b_fc,
        const void* W_mu, const void* b_mu, const void* W_sig, const void* b_sig,
        const void* A_log, const float* ysg, void* out) {
    __shared__ float yb[128];
    __shared__ float es[64];
    __shared__ float xs[128];
    if (((const u32*)A_log)[0] != 0u)
        heads_body<true >(W_out, W_fc, b_fc, W_mu, b_mu, W_sig, b_sig, ysg, out, yb, es, xs);
    else
        heads_body<false>(W_out, W_fc, b_fc, W_mu, b_mu, W_sig, b_sig, ysg, out, yb, es, xs);
}

extern "C" void kernel_launch(void* const* d_in, const int* in_sizes, int n_in,
                              void* d_out, int out_size, void* d_ws, size_t ws_size,
                              hipStream_t stream) {
    (void)in_sizes; (void)n_in; (void)ws_size; (void)out_size;
    char* ws = (char*)d_ws;
    u16*    zws = (u16*)(ws + ZWS_OFF);
    u16*    wp  = (u16*)(ws + WP_OFF);
    float4* psg = (float4*)(ws + PSG_OFF);
    float*  BCg = (float*)(ws + BC_OFF);
    float*  ysg = (float*)(ws + YS_OFF);

    // 0) pack W_enc into aligned MFMA panels
    pack_wenc<<<184, 256, 0, stream>>>(d_in[1], d_in[9], wp);
    // 1) encoder GEMM: 512 blocks x 4 waves, 32-row M-tile (halved B traffic),
    //    coalesced LDS-staged A, counted-wait single-buffer pipeline
    enc_gemm<<<512, 256, 0, stream>>>(d_in[0], d_in[2], d_in[9], wp, zws);
    // 2) parallel prep over (batch, chunk)
    prep<<<512, 256, 0, stream>>>(d_in[3], d_in[4], d_in[5], d_in[6], d_in[7],
                                  d_in[8], d_in[10], d_in[9], zws, psg, BCg);
    // 3) selective scan, one thread per (d, n) chain
    scan_k<<<256, 512, 0, stream>>>(d_in[9], psg, BCg, ysg);
    // 4) heads
    heads_k<<<64, 256, 0, stream>>>(d_in[11], d_in[12], d_in[13], d_in[14],
                                    d_in[15], d_in[16], d_in[17], d_in[9], ysg, d_out);
}